// Round 2
// baseline (5775.408 us; speedup 1.0000x reference)
//
#include <hip/hip_runtime.h>
#include <math.h>

#define Bq 16
#define Sq 1024
#define Dq 128
#define Hq 8
#define DHq 16
#define DFFq 512
#define Lq 3
#define NCLS 6
#define NROWS (Bq * Sq)   // 16384

// ---------------------------------------------------------------------------
// Tiled fp32 GEMM: C[M,N] = act(A[M,K] @ W[K,N] + bias[N])
// Tile 128x64, K-chunk 32, 256 threads, 8x4 micro-tile per thread.
// ---------------------------------------------------------------------------
#define GM 128
#define GN 64
#define GK 32

__global__ __launch_bounds__(256) void gemm_bias_act(
    const float* __restrict__ A, const float* __restrict__ W,
    const float* __restrict__ bias, float* __restrict__ C,
    int M, int N, int K, int do_relu)
{
    __shared__ float As[GM][GK + 1];
    __shared__ float Ws[GK][GN + 4];

    const int tid  = threadIdx.x;
    const int row0 = blockIdx.x * GM;
    const int col0 = blockIdx.y * GN;
    const int tr   = (tid >> 4) << 3;
    const int tc   = (tid & 15) << 2;

    const int ar = tid >> 3;
    const int ac = (tid & 7) << 2;
    const int wr = tid >> 4;
    const int wc = (tid & 15) << 2;

    float acc[8][4];
    #pragma unroll
    for (int i = 0; i < 8; ++i)
        #pragma unroll
        for (int j = 0; j < 4; ++j) acc[i][j] = 0.f;

    for (int k0 = 0; k0 < K; k0 += GK) {
        const float* Ap = A + (size_t)(row0 + ar) * K + k0 + ac;
        float4 a0 = *(const float4*)(Ap);
        float4 a1 = *(const float4*)(Ap + (size_t)32 * K);
        float4 a2 = *(const float4*)(Ap + (size_t)64 * K);
        float4 a3 = *(const float4*)(Ap + (size_t)96 * K);
        const float* Wp = W + (size_t)(k0 + wr) * N + col0 + wc;
        float4 w0 = *(const float4*)(Wp);
        float4 w1 = *(const float4*)(Wp + (size_t)16 * N);

        __syncthreads();

        As[ar][ac + 0] = a0.x; As[ar][ac + 1] = a0.y; As[ar][ac + 2] = a0.z; As[ar][ac + 3] = a0.w;
        As[ar + 32][ac + 0] = a1.x; As[ar + 32][ac + 1] = a1.y; As[ar + 32][ac + 2] = a1.z; As[ar + 32][ac + 3] = a1.w;
        As[ar + 64][ac + 0] = a2.x; As[ar + 64][ac + 1] = a2.y; As[ar + 64][ac + 2] = a2.z; As[ar + 64][ac + 3] = a2.w;
        As[ar + 96][ac + 0] = a3.x; As[ar + 96][ac + 1] = a3.y; As[ar + 96][ac + 2] = a3.z; As[ar + 96][ac + 3] = a3.w;
        *(float4*)&Ws[wr][wc]      = w0;
        *(float4*)&Ws[wr + 16][wc] = w1;

        __syncthreads();

        #pragma unroll
        for (int kk = 0; kk < GK; ++kk) {
            float a[8];
            #pragma unroll
            for (int i = 0; i < 8; ++i) a[i] = As[tr + i][kk];
            float4 wv = *(const float4*)&Ws[kk][tc];
            #pragma unroll
            for (int i = 0; i < 8; ++i) {
                acc[i][0] += a[i] * wv.x;
                acc[i][1] += a[i] * wv.y;
                acc[i][2] += a[i] * wv.z;
                acc[i][3] += a[i] * wv.w;
            }
        }
    }

    float4 bv = *(const float4*)&bias[col0 + tc];
    #pragma unroll
    for (int i = 0; i < 8; ++i) {
        float4 r;
        r.x = acc[i][0] + bv.x;
        r.y = acc[i][1] + bv.y;
        r.z = acc[i][2] + bv.z;
        r.w = acc[i][3] + bv.w;
        if (do_relu) {
            r.x = fmaxf(r.x, 0.f); r.y = fmaxf(r.y, 0.f);
            r.z = fmaxf(r.z, 0.f); r.w = fmaxf(r.w, 0.f);
        }
        *(float4*)&C[(size_t)(row0 + tr + i) * N + col0 + tc] = r;
    }
}

// ---------------------------------------------------------------------------
// Flash-style attention, fp32. 4 lanes per query row, each handling a
// 256-key chunk; no max-subtraction (scores are provably small for this
// model: LN'd inputs, W~N(0,0.05^2), ReLU => |s| < ~25, exp safe in fp32;
// softmax is shift-invariant so result is identical).
// grid.x = B*H*S*4/256 = 2048, block = 256.
// ---------------------------------------------------------------------------
__global__ __launch_bounds__(256) void attn_kernel(
    const float* __restrict__ q, const float* __restrict__ k,
    const float* __restrict__ v, float* __restrict__ o)
{
    const int gid = blockIdx.x * 256 + threadIdx.x;
    const int kc  = gid & 3;          // key chunk 0..3
    const int idx = gid >> 2;         // (b,h,r) flat: b*H*S + h*S + r
    const int b   = idx >> 13;        // / (H*S) = /8192
    const int h   = (idx >> 10) & 7;
    const int r   = idx & 1023;

    const size_t rowoff = ((size_t)(b * Sq + r)) * Dq + h * DHq;
    const float* qp = q + rowoff;

    float qv[16];
    {
        float4 t0 = *(const float4*)(qp + 0);
        float4 t1 = *(const float4*)(qp + 4);
        float4 t2 = *(const float4*)(qp + 8);
        float4 t3 = *(const float4*)(qp + 12);
        qv[0]=t0.x; qv[1]=t0.y; qv[2]=t0.z; qv[3]=t0.w;
        qv[4]=t1.x; qv[5]=t1.y; qv[6]=t1.z; qv[7]=t1.w;
        qv[8]=t2.x; qv[9]=t2.y; qv[10]=t2.z; qv[11]=t2.w;
        qv[12]=t3.x; qv[13]=t3.y; qv[14]=t3.z; qv[15]=t3.w;
    }

    const float* kp = k + ((size_t)b * Sq + kc * 256) * Dq + h * DHq;
    const float* vp = v + ((size_t)b * Sq + kc * 256) * Dq + h * DHq;

    float lsum = 0.f;
    float oa[16];
    #pragma unroll
    for (int d = 0; d < 16; ++d) oa[d] = 0.f;

    #pragma unroll 2
    for (int i = 0; i < 256; ++i) {
        float4 k0 = *(const float4*)(kp + 0);
        float4 k1 = *(const float4*)(kp + 4);
        float4 k2 = *(const float4*)(kp + 8);
        float4 k3 = *(const float4*)(kp + 12);
        float4 v0 = *(const float4*)(vp + 0);
        float4 v1 = *(const float4*)(vp + 4);
        float4 v2 = *(const float4*)(vp + 8);
        float4 v3 = *(const float4*)(vp + 12);
        kp += Dq; vp += Dq;

        float s0 = qv[0]*k0.x + qv[1]*k0.y + qv[2]*k0.z + qv[3]*k0.w;
        float s1 = qv[4]*k1.x + qv[5]*k1.y + qv[6]*k1.z + qv[7]*k1.w;
        float s2 = qv[8]*k2.x + qv[9]*k2.y + qv[10]*k2.z + qv[11]*k2.w;
        float s3 = qv[12]*k3.x + qv[13]*k3.y + qv[14]*k3.z + qv[15]*k3.w;
        float p = __expf(((s0 + s1) + (s2 + s3)) * 0.25f);
        lsum += p;

        oa[0]  = fmaf(p, v0.x, oa[0]);  oa[1]  = fmaf(p, v0.y, oa[1]);
        oa[2]  = fmaf(p, v0.z, oa[2]);  oa[3]  = fmaf(p, v0.w, oa[3]);
        oa[4]  = fmaf(p, v1.x, oa[4]);  oa[5]  = fmaf(p, v1.y, oa[5]);
        oa[6]  = fmaf(p, v1.z, oa[6]);  oa[7]  = fmaf(p, v1.w, oa[7]);
        oa[8]  = fmaf(p, v2.x, oa[8]);  oa[9]  = fmaf(p, v2.y, oa[9]);
        oa[10] = fmaf(p, v2.z, oa[10]); oa[11] = fmaf(p, v2.w, oa[11]);
        oa[12] = fmaf(p, v3.x, oa[12]); oa[13] = fmaf(p, v3.y, oa[13]);
        oa[14] = fmaf(p, v3.z, oa[14]); oa[15] = fmaf(p, v3.w, oa[15]);
    }

    // combine the 4 key-chunk partials (lanes kc=0..3 of each group)
    lsum += __shfl_xor(lsum, 1, 64);
    lsum += __shfl_xor(lsum, 2, 64);
    #pragma unroll
    for (int d = 0; d < 16; ++d) {
        oa[d] += __shfl_xor(oa[d], 1, 64);
        oa[d] += __shfl_xor(oa[d], 2, 64);
    }

    // each of the 4 lanes writes its 4-float slice => contiguous 64B per row
    const float inv = 1.f / lsum;
    float4 rslt;
    rslt.x = oa[kc * 4 + 0] * inv;
    rslt.y = oa[kc * 4 + 1] * inv;
    rslt.z = oa[kc * 4 + 2] * inv;
    rslt.w = oa[kc * 4 + 3] * inv;
    *(float4*)(o + rowoff + kc * 4) = rslt;
}

// ---------------------------------------------------------------------------
// out = LayerNorm(a + res) * g + b, rows of 128. One wave per row, 4 rows/block.
// ---------------------------------------------------------------------------
__global__ __launch_bounds__(256) void add_ln_kernel(
    const float* __restrict__ a, const float* __restrict__ res,
    const float* __restrict__ g, const float* __restrict__ bb,
    float* __restrict__ out, float eps)
{
    const int wave = threadIdx.x >> 6;
    const int lane = threadIdx.x & 63;
    const int row  = blockIdx.x * 4 + wave;
    const size_t base = (size_t)row * Dq;

    float v0 = a[base + lane]      + res[base + lane];
    float v1 = a[base + 64 + lane] + res[base + 64 + lane];

    float s = v0 + v1;
    #pragma unroll
    for (int off = 32; off > 0; off >>= 1) s += __shfl_xor(s, off, 64);
    const float mu = s * (1.f / 128.f);

    const float d0 = v0 - mu, d1 = v1 - mu;
    float vs = d0 * d0 + d1 * d1;
    #pragma unroll
    for (int off = 32; off > 0; off >>= 1) vs += __shfl_xor(vs, off, 64);
    const float rstd = rsqrtf(vs * (1.f / 128.f) + eps);

    out[base + lane]      = g[lane]      * d0 * rstd + bb[lane];
    out[base + 64 + lane] = g[lane + 64] * d1 * rstd + bb[lane + 64];
}

// ---------------------------------------------------------------------------
// Final projection: out[row, c] = x[row,:] @ Wout[:, c] + bout[c], c < 6.
// ---------------------------------------------------------------------------
__global__ __launch_bounds__(256) void final_proj_kernel(
    const float* __restrict__ x, const float* __restrict__ Wout,
    const float* __restrict__ bout, float* __restrict__ out)
{
    const int gid = blockIdx.x * 256 + threadIdx.x;
    const int row = gid >> 3;
    const int c   = gid & 7;
    if (row >= NROWS || c >= NCLS) return;
    const float* xr = x + (size_t)row * Dq;
    float acc = bout[c];
    #pragma unroll 16
    for (int kk = 0; kk < Dq; ++kk) acc += xr[kk] * Wout[kk * NCLS + c];
    out[(size_t)row * NCLS + c] = acc;
}

// ---------------------------------------------------------------------------
extern "C" void kernel_launch(void* const* d_in, const int* in_sizes, int n_in,
                              void* d_out, int out_size, void* d_ws, size_t ws_size,
                              hipStream_t stream)
{
    const float* x_in  = (const float*)d_in[0];
    const float* Wq    = (const float*)d_in[1];
    const float* bq    = (const float*)d_in[2];
    const float* Wk    = (const float*)d_in[3];
    const float* bk    = (const float*)d_in[4];
    const float* Wv    = (const float*)d_in[5];
    const float* bv    = (const float*)d_in[6];
    const float* ln1_g = (const float*)d_in[7];
    const float* ln1_b = (const float*)d_in[8];
    const float* W1    = (const float*)d_in[9];
    const float* b1    = (const float*)d_in[10];
    const float* W2    = (const float*)d_in[11];
    const float* b2    = (const float*)d_in[12];
    const float* ln2_g = (const float*)d_in[13];
    const float* ln2_b = (const float*)d_in[14];
    const float* Wout  = (const float*)d_in[15];
    const float* bout  = (const float*)d_in[16];
    float* out = (float*)d_out;

    const size_t NX = (size_t)NROWS * Dq;         // 2M floats
    float* ws   = (float*)d_ws;
    float* qbuf = ws;                 // 2M
    float* kbuf = ws + NX;            // 2M
    float* vbuf = ws + 2 * NX;        // 2M
    float* obuf = ws + 3 * NX;        // 2M
    float* hbuf = ws;                 // 8M, aliases q..o (dead by FFN1 time)
    float* fbuf = ws + 4 * NX;        // 2M
    float* xa   = ws + 5 * NX;        // 2M
    float* xb   = ws + 6 * NX;        // 2M

    const dim3 blk(256);
    const dim3 g_qkv(NROWS / GM, Dq / GN);     // (128, 2)
    const dim3 g_ffn1(NROWS / GM, DFFq / GN);  // (128, 8)
    const dim3 g_ffn2(NROWS / GM, Dq / GN);    // (128, 2)

    const float* xcur = x_in;
    for (int l = 0; l < Lq; ++l) {
        const float* wql = Wq + (size_t)l * Dq * Dq;
        const float* wkl = Wk + (size_t)l * Dq * Dq;
        const float* wvl = Wv + (size_t)l * Dq * Dq;

        gemm_bias_act<<<g_qkv, blk, 0, stream>>>(xcur, wql, bq + l * Dq, qbuf, NROWS, Dq, Dq, 1);
        gemm_bias_act<<<g_qkv, blk, 0, stream>>>(xcur, wkl, bk + l * Dq, kbuf, NROWS, Dq, Dq, 1);
        gemm_bias_act<<<g_qkv, blk, 0, stream>>>(xcur, wvl, bv + l * Dq, vbuf, NROWS, Dq, Dq, 1);

        attn_kernel<<<dim3(Bq * Hq * Sq * 4 / 256), blk, 0, stream>>>(qbuf, kbuf, vbuf, obuf);

        add_ln_kernel<<<dim3(NROWS / 4), blk, 0, stream>>>(obuf, xcur, ln1_g + l * Dq,
                                                           ln1_b + l * Dq, xa, 1e-8f);

        gemm_bias_act<<<g_ffn1, blk, 0, stream>>>(xa, W1 + (size_t)l * Dq * DFFq,
                                                  b1 + l * DFFq, hbuf, NROWS, DFFq, Dq, 1);
        gemm_bias_act<<<g_ffn2, blk, 0, stream>>>(hbuf, W2 + (size_t)l * DFFq * Dq,
                                                  b2 + l * Dq, fbuf, NROWS, Dq, DFFq, 0);

        add_ln_kernel<<<dim3(NROWS / 4), blk, 0, stream>>>(fbuf, xa, ln2_g + l * Dq,
                                                           ln2_b + l * Dq, xb, 1e-6f);
        xcur = xb;
    }

    final_proj_kernel<<<dim3(NROWS * 8 / 256), blk, 0, stream>>>(xcur, Wout, bout, out);
}

// Round 3
// 892.507 us; speedup vs baseline: 6.4710x; 6.4710x over previous
//
#include <hip/hip_runtime.h>
#include <math.h>

#define Bq 16
#define Sq 1024
#define Dq 128
#define Hq 8
#define DHq 16
#define DFFq 512
#define Lq 3
#define NCLS 6
#define NROWS (Bq * Sq)       // 16384
#define BHS (Bq * Hq * Sq)    // 131072

// ---------------------------------------------------------------------------
// Tiled fp32 GEMM: C[M,N] = act(A[M,K] @ W[K,N] + bias[N])
// ---------------------------------------------------------------------------
#define GM 128
#define GN 64
#define GK 32

__global__ __launch_bounds__(256) void gemm_bias_act(
    const float* __restrict__ A, const float* __restrict__ W,
    const float* __restrict__ bias, float* __restrict__ C,
    int M, int N, int K, int do_relu)
{
    __shared__ float As[GM][GK + 1];
    __shared__ float Ws[GK][GN + 4];

    const int tid  = threadIdx.x;
    const int row0 = blockIdx.x * GM;
    const int col0 = blockIdx.y * GN;
    const int tr   = (tid >> 4) << 3;
    const int tc   = (tid & 15) << 2;

    const int ar = tid >> 3;
    const int ac = (tid & 7) << 2;
    const int wr = tid >> 4;
    const int wc = (tid & 15) << 2;

    float acc[8][4];
    #pragma unroll
    for (int i = 0; i < 8; ++i)
        #pragma unroll
        for (int j = 0; j < 4; ++j) acc[i][j] = 0.f;

    for (int k0 = 0; k0 < K; k0 += GK) {
        const float* Ap = A + (size_t)(row0 + ar) * K + k0 + ac;
        float4 a0 = *(const float4*)(Ap);
        float4 a1 = *(const float4*)(Ap + (size_t)32 * K);
        float4 a2 = *(const float4*)(Ap + (size_t)64 * K);
        float4 a3 = *(const float4*)(Ap + (size_t)96 * K);
        const float* Wp = W + (size_t)(k0 + wr) * N + col0 + wc;
        float4 w0 = *(const float4*)(Wp);
        float4 w1 = *(const float4*)(Wp + (size_t)16 * N);

        __syncthreads();

        As[ar][ac + 0] = a0.x; As[ar][ac + 1] = a0.y; As[ar][ac + 2] = a0.z; As[ar][ac + 3] = a0.w;
        As[ar + 32][ac + 0] = a1.x; As[ar + 32][ac + 1] = a1.y; As[ar + 32][ac + 2] = a1.z; As[ar + 32][ac + 3] = a1.w;
        As[ar + 64][ac + 0] = a2.x; As[ar + 64][ac + 1] = a2.y; As[ar + 64][ac + 2] = a2.z; As[ar + 64][ac + 3] = a2.w;
        As[ar + 96][ac + 0] = a3.x; As[ar + 96][ac + 1] = a3.y; As[ar + 96][ac + 2] = a3.z; As[ar + 96][ac + 3] = a3.w;
        *(float4*)&Ws[wr][wc]      = w0;
        *(float4*)&Ws[wr + 16][wc] = w1;

        __syncthreads();

        #pragma unroll
        for (int kk = 0; kk < GK; ++kk) {
            float a[8];
            #pragma unroll
            for (int i = 0; i < 8; ++i) a[i] = As[tr + i][kk];
            float4 wv = *(const float4*)&Ws[kk][tc];
            #pragma unroll
            for (int i = 0; i < 8; ++i) {
                acc[i][0] += a[i] * wv.x;
                acc[i][1] += a[i] * wv.y;
                acc[i][2] += a[i] * wv.z;
                acc[i][3] += a[i] * wv.w;
            }
        }
    }

    float4 bv = *(const float4*)&bias[col0 + tc];
    #pragma unroll
    for (int i = 0; i < 8; ++i) {
        float4 r;
        r.x = acc[i][0] + bv.x;
        r.y = acc[i][1] + bv.y;
        r.z = acc[i][2] + bv.z;
        r.w = acc[i][3] + bv.w;
        if (do_relu) {
            r.x = fmaxf(r.x, 0.f); r.y = fmaxf(r.y, 0.f);
            r.z = fmaxf(r.z, 0.f); r.w = fmaxf(r.w, 0.f);
        }
        *(float4*)&C[(size_t)(row0 + tr + i) * N + col0 + tc] = r;
    }
}

// ---------------------------------------------------------------------------
// Attention partial: grid (nkc, 4, B*H). Block = 256 threads = 256 query rows
// of one (b,h); ALL lanes read the SAME K/V row each iteration (wave-uniform
// broadcast loads — the pattern R1 proved fast; R2 proved lane-split kills it).
// Key chunk kc = blockIdx.x handles kch keys. No max-subtraction (scores are
// bounded for this model; softmax shift-invariant — validated in R2).
// norm==1 (nkc==1): writes normalized o rows directly (part_o = o buffer).
// norm==0: writes raw (oa[16], lsum) partials for reduce_add_ln.
// ---------------------------------------------------------------------------
__global__ __launch_bounds__(256) void attn_partial(
    const float* __restrict__ q, const float* __restrict__ k,
    const float* __restrict__ v, float* __restrict__ part_o,
    float* __restrict__ part_l, int kch, int norm)
{
    const int kc = blockIdx.x;
    const int qc = blockIdx.y;
    const int bh = blockIdx.z;
    const int b  = bh >> 3;
    const int h  = bh & 7;
    const int r  = qc * 256 + threadIdx.x;

    const size_t rowoff = ((size_t)(b * Sq + r)) * Dq + h * DHq;
    const float* qp = q + rowoff;

    float qv[16];
    {
        float4 t0 = *(const float4*)(qp + 0);
        float4 t1 = *(const float4*)(qp + 4);
        float4 t2 = *(const float4*)(qp + 8);
        float4 t3 = *(const float4*)(qp + 12);
        qv[0]=t0.x*0.25f; qv[1]=t0.y*0.25f; qv[2]=t0.z*0.25f; qv[3]=t0.w*0.25f;
        qv[4]=t1.x*0.25f; qv[5]=t1.y*0.25f; qv[6]=t1.z*0.25f; qv[7]=t1.w*0.25f;
        qv[8]=t2.x*0.25f; qv[9]=t2.y*0.25f; qv[10]=t2.z*0.25f; qv[11]=t2.w*0.25f;
        qv[12]=t3.x*0.25f; qv[13]=t3.y*0.25f; qv[14]=t3.z*0.25f; qv[15]=t3.w*0.25f;
    }

    const float* kp = k + ((size_t)b * Sq + (size_t)kc * kch) * Dq + h * DHq;
    const float* vp = v + ((size_t)b * Sq + (size_t)kc * kch) * Dq + h * DHq;

    float lsum = 0.f;
    float oa[16];
    #pragma unroll
    for (int d = 0; d < 16; ++d) oa[d] = 0.f;

    #pragma unroll 2
    for (int i = 0; i < kch; ++i) {
        float4 k0 = *(const float4*)(kp + 0);
        float4 k1 = *(const float4*)(kp + 4);
        float4 k2 = *(const float4*)(kp + 8);
        float4 k3 = *(const float4*)(kp + 12);
        float4 v0 = *(const float4*)(vp + 0);
        float4 v1 = *(const float4*)(vp + 4);
        float4 v2 = *(const float4*)(vp + 8);
        float4 v3 = *(const float4*)(vp + 12);
        kp += Dq; vp += Dq;

        float s0 = fmaf(qv[0],k0.x, fmaf(qv[1],k0.y, fmaf(qv[2],k0.z, qv[3]*k0.w)));
        float s1 = fmaf(qv[4],k1.x, fmaf(qv[5],k1.y, fmaf(qv[6],k1.z, qv[7]*k1.w)));
        float s2 = fmaf(qv[8],k2.x, fmaf(qv[9],k2.y, fmaf(qv[10],k2.z, qv[11]*k2.w)));
        float s3 = fmaf(qv[12],k3.x, fmaf(qv[13],k3.y, fmaf(qv[14],k3.z, qv[15]*k3.w)));
        float p = __expf((s0 + s1) + (s2 + s3));
        lsum += p;

        oa[0]  = fmaf(p, v0.x, oa[0]);  oa[1]  = fmaf(p, v0.y, oa[1]);
        oa[2]  = fmaf(p, v0.z, oa[2]);  oa[3]  = fmaf(p, v0.w, oa[3]);
        oa[4]  = fmaf(p, v1.x, oa[4]);  oa[5]  = fmaf(p, v1.y, oa[5]);
        oa[6]  = fmaf(p, v1.z, oa[6]);  oa[7]  = fmaf(p, v1.w, oa[7]);
        oa[8]  = fmaf(p, v2.x, oa[8]);  oa[9]  = fmaf(p, v2.y, oa[9]);
        oa[10] = fmaf(p, v2.z, oa[10]); oa[11] = fmaf(p, v2.w, oa[11]);
        oa[12] = fmaf(p, v3.x, oa[12]); oa[13] = fmaf(p, v3.y, oa[13]);
        oa[14] = fmaf(p, v3.z, oa[14]); oa[15] = fmaf(p, v3.w, oa[15]);
    }

    if (norm) {
        const float inv = 1.f / lsum;
        float* op = part_o + rowoff;   // part_o doubles as [B,S,D] o buffer
        float4 r0, r1, r2, r3;
        r0.x=oa[0]*inv;  r0.y=oa[1]*inv;  r0.z=oa[2]*inv;  r0.w=oa[3]*inv;
        r1.x=oa[4]*inv;  r1.y=oa[5]*inv;  r1.z=oa[6]*inv;  r1.w=oa[7]*inv;
        r2.x=oa[8]*inv;  r2.y=oa[9]*inv;  r2.z=oa[10]*inv; r2.w=oa[11]*inv;
        r3.x=oa[12]*inv; r3.y=oa[13]*inv; r3.z=oa[14]*inv; r3.w=oa[15]*inv;
        *(float4*)(op + 0)  = r0;
        *(float4*)(op + 4)  = r1;
        *(float4*)(op + 8)  = r2;
        *(float4*)(op + 12) = r3;
    } else {
        const size_t p = (size_t)kc * BHS + (size_t)bh * Sq + r;
        float* po = part_o + p * 16;
        *(float4*)(po + 0)  = make_float4(oa[0],  oa[1],  oa[2],  oa[3]);
        *(float4*)(po + 4)  = make_float4(oa[4],  oa[5],  oa[6],  oa[7]);
        *(float4*)(po + 8)  = make_float4(oa[8],  oa[9],  oa[10], oa[11]);
        *(float4*)(po + 12) = make_float4(oa[12], oa[13], oa[14], oa[15]);
        part_l[p] = lsum;
    }
}

// ---------------------------------------------------------------------------
// Fused: o = softmax-combine(partials); out = LayerNorm(o + res)*g + b.
// One wave per query row (full 128-dim), 4 rows/block.
// ---------------------------------------------------------------------------
__global__ __launch_bounds__(256) void reduce_add_ln(
    const float* __restrict__ part_o, const float* __restrict__ part_l,
    const float* __restrict__ res, const float* __restrict__ g,
    const float* __restrict__ bb, float* __restrict__ out,
    float eps, int nkc)
{
    const int wave = threadIdx.x >> 6;
    const int lane = threadIdx.x & 63;
    const int row  = blockIdx.x * 4 + wave;      // global query row
    const int b    = row >> 10;
    const int r    = row & 1023;
    const size_t base = (size_t)row * Dq;

    const int h0  = lane >> 4;          // head for d = lane
    const int h1  = h0 + 4;             // head for d = lane + 64
    const int dd  = lane & 15;
    const size_t p0 = (size_t)(b * Hq + h0) * Sq + r;
    const size_t p1 = (size_t)(b * Hq + h1) * Sq + r;

    float v0 = 0.f, l0 = 0.f, v1 = 0.f, l1 = 0.f;
    for (int kc = 0; kc < nkc; ++kc) {
        const size_t off = (size_t)kc * BHS;
        v0 += part_o[(off + p0) * 16 + dd];
        l0 += part_l[off + p0];
        v1 += part_o[(off + p1) * 16 + dd];
        l1 += part_l[off + p1];
    }
    v0 = v0 / l0 + res[base + lane];
    v1 = v1 / l1 + res[base + 64 + lane];

    float s = v0 + v1;
    #pragma unroll
    for (int off = 32; off > 0; off >>= 1) s += __shfl_xor(s, off, 64);
    const float mu = s * (1.f / 128.f);

    const float d0 = v0 - mu, d1 = v1 - mu;
    float vs = d0 * d0 + d1 * d1;
    #pragma unroll
    for (int off = 32; off > 0; off >>= 1) vs += __shfl_xor(vs, off, 64);
    const float rstd = rsqrtf(vs * (1.f / 128.f) + eps);

    out[base + lane]      = g[lane]      * d0 * rstd + bb[lane];
    out[base + 64 + lane] = g[lane + 64] * d1 * rstd + bb[lane + 64];
}

// ---------------------------------------------------------------------------
// out = LayerNorm(a + res) * g + b (plain version, for ln2 / fallback ln1)
// ---------------------------------------------------------------------------
__global__ __launch_bounds__(256) void add_ln_kernel(
    const float* __restrict__ a, const float* __restrict__ res,
    const float* __restrict__ g, const float* __restrict__ bb,
    float* __restrict__ out, float eps)
{
    const int wave = threadIdx.x >> 6;
    const int lane = threadIdx.x & 63;
    const int row  = blockIdx.x * 4 + wave;
    const size_t base = (size_t)row * Dq;

    float v0 = a[base + lane]      + res[base + lane];
    float v1 = a[base + 64 + lane] + res[base + 64 + lane];

    float s = v0 + v1;
    #pragma unroll
    for (int off = 32; off > 0; off >>= 1) s += __shfl_xor(s, off, 64);
    const float mu = s * (1.f / 128.f);

    const float d0 = v0 - mu, d1 = v1 - mu;
    float vs = d0 * d0 + d1 * d1;
    #pragma unroll
    for (int off = 32; off > 0; off >>= 1) vs += __shfl_xor(vs, off, 64);
    const float rstd = rsqrtf(vs * (1.f / 128.f) + eps);

    out[base + lane]      = g[lane]      * d0 * rstd + bb[lane];
    out[base + 64 + lane] = g[lane + 64] * d1 * rstd + bb[lane + 64];
}

// ---------------------------------------------------------------------------
__global__ __launch_bounds__(256) void final_proj_kernel(
    const float* __restrict__ x, const float* __restrict__ Wout,
    const float* __restrict__ bout, float* __restrict__ out)
{
    const int gid = blockIdx.x * 256 + threadIdx.x;
    const int row = gid >> 3;
    const int c   = gid & 7;
    if (row >= NROWS || c >= NCLS) return;
    const float* xr = x + (size_t)row * Dq;
    float acc = bout[c];
    #pragma unroll 16
    for (int kk = 0; kk < Dq; ++kk) acc += xr[kk] * Wout[kk * NCLS + c];
    out[(size_t)row * NCLS + c] = acc;
}

// ---------------------------------------------------------------------------
extern "C" void kernel_launch(void* const* d_in, const int* in_sizes, int n_in,
                              void* d_out, int out_size, void* d_ws, size_t ws_size,
                              hipStream_t stream)
{
    const float* x_in  = (const float*)d_in[0];
    const float* Wq    = (const float*)d_in[1];
    const float* bq    = (const float*)d_in[2];
    const float* Wk    = (const float*)d_in[3];
    const float* bk    = (const float*)d_in[4];
    const float* Wv    = (const float*)d_in[5];
    const float* bv    = (const float*)d_in[6];
    const float* ln1_g = (const float*)d_in[7];
    const float* ln1_b = (const float*)d_in[8];
    const float* W1    = (const float*)d_in[9];
    const float* b1    = (const float*)d_in[10];
    const float* W2    = (const float*)d_in[11];
    const float* b2    = (const float*)d_in[12];
    const float* ln2_g = (const float*)d_in[13];
    const float* ln2_b = (const float*)d_in[14];
    const float* Wout  = (const float*)d_in[15];
    const float* bout  = (const float*)d_in[16];
    float* out = (float*)d_out;

    const size_t NX = (size_t)NROWS * Dq;   // 2,097,152 floats
    float* ws = (float*)d_ws;

    // Primary layout (key-split 2): q,k,v | part_o(2NX) | part_l(BHS*2) |
    // xa | xb | fbuf.  hbuf(4NX) aliases q,k,v,part_o[0:NX] (all dead by FFN1).
    const size_t primary_floats = 8 * NX + (size_t)2 * BHS;
    const bool big_ws = ws_size >= primary_floats * sizeof(float);

    float *qbuf, *kbuf, *vbuf, *part_o, *part_l, *xa, *xb, *fbuf, *hbuf, *obuf;
    int nkc, kch, norm;
    if (big_ws) {
        qbuf   = ws;
        kbuf   = ws + NX;
        vbuf   = ws + 2 * NX;
        part_o = ws + 3 * NX;               // 2NX
        part_l = ws + 5 * NX;               // 2*BHS
        xa     = ws + 5 * NX + 2 * BHS;
        xb     = xa + NX;
        fbuf   = xb + NX;
        hbuf   = ws;                        // 4NX, aliases q,k,v,part_o-front
        obuf   = nullptr;
        nkc = 2; kch = Sq / 2; norm = 0;
    } else {
        // R1-proven 7NX layout, split=1 (normalize in-kernel, plain add_ln)
        qbuf   = ws;
        kbuf   = ws + NX;
        vbuf   = ws + 2 * NX;
        obuf   = ws + 3 * NX;
        fbuf   = ws + 4 * NX;
        xa     = ws + 5 * NX;
        xb     = ws + 6 * NX;
        hbuf   = ws;                        // 4NX, aliases q,k,v,o
        part_o = obuf; part_l = obuf;       // part_l unused when norm=1
        nkc = 1; kch = Sq; norm = 1;
    }

    const dim3 blk(256);
    const dim3 g_qkv(NROWS / GM, Dq / GN);
    const dim3 g_ffn1(NROWS / GM, DFFq / GN);
    const dim3 g_ffn2(NROWS / GM, Dq / GN);
    const dim3 g_attn(nkc, 4, Bq * Hq);

    const float* xcur = x_in;
    for (int l = 0; l < Lq; ++l) {
        const float* wql = Wq + (size_t)l * Dq * Dq;
        const float* wkl = Wk + (size_t)l * Dq * Dq;
        const float* wvl = Wv + (size_t)l * Dq * Dq;

        gemm_bias_act<<<g_qkv, blk, 0, stream>>>(xcur, wql, bq + l * Dq, qbuf, NROWS, Dq, Dq, 1);
        gemm_bias_act<<<g_qkv, blk, 0, stream>>>(xcur, wkl, bk + l * Dq, kbuf, NROWS, Dq, Dq, 1);
        gemm_bias_act<<<g_qkv, blk, 0, stream>>>(xcur, wvl, bv + l * Dq, vbuf, NROWS, Dq, Dq, 1);

        attn_partial<<<g_attn, blk, 0, stream>>>(qbuf, kbuf, vbuf, part_o, part_l, kch, norm);

        if (big_ws) {
            reduce_add_ln<<<dim3(NROWS / 4), blk, 0, stream>>>(
                part_o, part_l, xcur, ln1_g + l * Dq, ln1_b + l * Dq, xa, 1e-8f, nkc);
        } else {
            add_ln_kernel<<<dim3(NROWS / 4), blk, 0, stream>>>(
                obuf, xcur, ln1_g + l * Dq, ln1_b + l * Dq, xa, 1e-8f);
        }

        gemm_bias_act<<<g_ffn1, blk, 0, stream>>>(xa, W1 + (size_t)l * Dq * DFFq,
                                                  b1 + l * DFFq, hbuf, NROWS, DFFq, Dq, 1);
        gemm_bias_act<<<g_ffn2, blk, 0, stream>>>(hbuf, W2 + (size_t)l * DFFq * Dq,
                                                  b2 + l * Dq, fbuf, NROWS, Dq, DFFq, 0);

        add_ln_kernel<<<dim3(NROWS / 4), blk, 0, stream>>>(fbuf, xa, ln2_g + l * Dq,
                                                           ln2_b + l * Dq, xb, 1e-6f);
        xcur = xb;
    }

    final_proj_kernel<<<dim3(NROWS * 8 / 256), blk, 0, stream>>>(xcur, Wout, bout, out);
}

// Round 5
// 706.078 us; speedup vs baseline: 8.1796x; 1.2640x over previous
//
#include <hip/hip_runtime.h>
#include <math.h>

#define Bq 16
#define Sq 1024
#define Dq 128
#define Hq 8
#define DHq 16
#define DFFq 512
#define Lq 3
#define NCLS 6
#define NROWS (Bq * Sq)       // 16384
#define NX ((size_t)NROWS * Dq)   // 2,097,152 floats

typedef __attribute__((ext_vector_type(8))) short    bf16x8;
typedef __attribute__((ext_vector_type(4))) float    f32x4;
typedef __attribute__((ext_vector_type(4))) _Float16 f16x4;

__device__ inline ushort f32_to_bf16(float f) {
    union { float f; unsigned u; } v; v.f = f;
    unsigned r = v.u + 0x7fffu + ((v.u >> 16) & 1u);
    return (ushort)(r >> 16);
}

// ---------------------------------------------------------------------------
// prep: cast+transpose all weights to bf16 (Wt[n][k]) and cast x to bf16.
// Flat grid over 2,637,824 elements.
// Weight ws layout (bf16 elts): QKVT: (w*3+l)*16384 + n*128 + k   (w=0,1,2)
//                                W1T : 147456 + l*65536 + n*128 + k  (n<512)
//                                W2T : 344064 + l*65536 + n*512 + k  (n<128)
// ---------------------------------------------------------------------------
__global__ __launch_bounds__(256) void prep_kernel(
    const float* __restrict__ Wqp, const float* __restrict__ Wkp,
    const float* __restrict__ Wvp, const float* __restrict__ W1p,
    const float* __restrict__ W2p, const float* __restrict__ xp,
    ushort* __restrict__ wbf, ushort* __restrict__ xbf)
{
    const int gid = blockIdx.x * 256 + threadIdx.x;
    if (gid < 147456) {                       // QKV transpose
        const int w   = gid / 49152;
        const int rem = gid - w * 49152;
        const int l   = rem >> 14;
        const int idx = rem & 16383;
        const int k   = idx >> 7;
        const int n   = idx & 127;
        const float* src = (w == 0) ? Wqp : (w == 1) ? Wkp : Wvp;
        wbf[(size_t)(w * 3 + l) * 16384 + n * 128 + k] =
            f32_to_bf16(src[(size_t)l * 16384 + k * 128 + n]);
    } else if (gid < 344064) {                // W1 transpose [128][512]->[512][128]
        const int g   = gid - 147456;
        const int l   = g >> 16;
        const int idx = g & 65535;
        const int k   = idx >> 9;
        const int n   = idx & 511;
        wbf[147456 + (size_t)l * 65536 + n * 128 + k] =
            f32_to_bf16(W1p[(size_t)l * 65536 + k * 512 + n]);
    } else if (gid < 540672) {                // W2 transpose [512][128]->[128][512]
        const int g   = gid - 344064;
        const int l   = g >> 16;
        const int idx = g & 65535;
        const int k   = idx >> 7;
        const int n   = idx & 127;
        wbf[344064 + (size_t)l * 65536 + n * 512 + k] =
            f32_to_bf16(W2p[(size_t)l * 65536 + k * 128 + n]);
    } else {                                  // x cast
        const int g = gid - 540672;
        xbf[g] = f32_to_bf16(xp[g]);
    }
}

// ---------------------------------------------------------------------------
// bf16 MFMA GEMM: C[M,N] = act(A[M,K] @ Bt[N,K]^T + bias), tile 64x128, BK=32.
// 256 thr = 4 waves, wave (wm,wn) computes 32x64 via 2x4 16x16x32 MFMAs.
// LDS rows padded to 40 bf16 (80 B) -> 2-way-max bank aliasing (free).
// mode: 0 relu->f16 [M][ldo] | 1 relu->f16 vt-layout [b][h][dh][s]
//       2 relu->bf16 [M][ldo] | 3 linear->f32 [M][ldo]
// ---------------------------------------------------------------------------
__global__ __launch_bounds__(256) void gemm_mfma(
    const ushort* __restrict__ A, const ushort* __restrict__ Bt,
    const float* __restrict__ bias, void* __restrict__ out,
    int K, int ldo, int mode)
{
    __shared__ ushort As[64 * 40];
    __shared__ ushort Bs[128 * 40];

    const int tid  = threadIdx.x;
    const int row0 = blockIdx.x * 64;
    const int col0 = blockIdx.y * 128;
    const int wave = tid >> 6;
    const int lane = tid & 63;
    const int quad = lane >> 4;
    const int m16  = lane & 15;
    const int wm   = wave >> 1;          // 0,1 -> row block
    const int wn   = wave & 1;           // 0,1 -> col block

    const int sar = tid >> 2;            // A stage row 0..63
    const int sac = (tid & 3) * 8;       // A stage col 0,8,16,24

    f32x4 acc[2][4];
    #pragma unroll
    for (int i = 0; i < 2; ++i)
        #pragma unroll
        for (int j = 0; j < 4; ++j) acc[i][j] = (f32x4)0.f;

    for (int k0 = 0; k0 < K; k0 += 32) {
        bf16x8 av = *(const bf16x8*)(A + (size_t)(row0 + sar) * K + k0 + sac);
        const int r1 = tid >> 2, r2 = r1 + 64;
        bf16x8 bv1 = *(const bf16x8*)(Bt + (size_t)(col0 + r1) * K + k0 + sac);
        bf16x8 bv2 = *(const bf16x8*)(Bt + (size_t)(col0 + r2) * K + k0 + sac);

        __syncthreads();
        *(bf16x8*)&As[sar * 40 + sac] = av;
        *(bf16x8*)&Bs[r1 * 40 + sac]  = bv1;
        *(bf16x8*)&Bs[r2 * 40 + sac]  = bv2;
        __syncthreads();

        bf16x8 af[2], bf[4];
        #pragma unroll
        for (int i = 0; i < 2; ++i)
            af[i] = *(const bf16x8*)&As[(32 * wm + 16 * i + m16) * 40 + quad * 8];
        #pragma unroll
        for (int j = 0; j < 4; ++j)
            bf[j] = *(const bf16x8*)&Bs[(64 * wn + 16 * j + m16) * 40 + quad * 8];
        #pragma unroll
        for (int i = 0; i < 2; ++i)
            #pragma unroll
            for (int j = 0; j < 4; ++j)
                acc[i][j] = __builtin_amdgcn_mfma_f32_16x16x32_bf16(af[i], bf[j], acc[i][j], 0, 0, 0);
    }

    float bias_v[4];
    #pragma unroll
    for (int j = 0; j < 4; ++j) bias_v[j] = bias[col0 + 64 * wn + 16 * j + m16];

    #pragma unroll
    for (int i = 0; i < 2; ++i) {
        #pragma unroll
        for (int j = 0; j < 4; ++j) {
            const int col = col0 + 64 * wn + 16 * j + m16;
            #pragma unroll
            for (int r = 0; r < 4; ++r) {
                float val = acc[i][j][r] + bias_v[j];
                if (mode != 3) val = fmaxf(val, 0.f);
                const int gr = row0 + 32 * wm + 16 * i + quad * 4 + r;
                if (mode == 0) {
                    ((_Float16*)out)[(size_t)gr * ldo + col] = (_Float16)val;
                } else if (mode == 1) {
                    const int b = gr >> 10, s = gr & 1023;
                    const int hh = col >> 4, dh = col & 15;
                    ((_Float16*)out)[(((size_t)b * Hq + hh) * DHq + dh) * Sq + s] = (_Float16)val;
                } else if (mode == 2) {
                    ((ushort*)out)[(size_t)gr * ldo + col] = f32_to_bf16(val);
                } else {
                    ((float*)out)[(size_t)gr * ldo + col] = val;
                }
            }
        }
    }
}

// ---------------------------------------------------------------------------
// f16 MFMA flash attention. grid(bh=128, qc=16), block 256 = 4 waves.
// Wave w: 16 queries q0 = qc*64 + w*16, loops 64 key-tiles of 16.
// S^T tile = mfma_16x16x16f16(Kfrag-as-A, Qfrag-as-B)  -> lane: q=lane&15,
// key=quad*4+reg.  P^T C-layout == A-operand layout of the PV mfma (m=q,
// k=key), so P feeds PV directly.  V pre-transposed [b][h][dh][s] f16.
// No max-subtraction (validated R2/R3).  One block = full softmax for its
// queries -> writes final o, no reduction pass.
// ---------------------------------------------------------------------------
__global__ __launch_bounds__(256) void attn_mfma(
    const _Float16* __restrict__ q, const _Float16* __restrict__ k,
    const _Float16* __restrict__ vt, float* __restrict__ o)
{
    const int bh   = blockIdx.x;
    const int qc   = blockIdx.y;
    const int b    = bh >> 3;
    const int h    = bh & 7;
    const int wave = threadIdx.x >> 6;
    const int lane = threadIdx.x & 63;
    const int quad = lane >> 4;
    const int m16  = lane & 15;
    const int q0   = qc * 64 + wave * 16;

    // Q fragment (B-operand): Q[q=m16][dh=quad*4+j]
    const f16x4 qf = *(const f16x4*)(q + ((size_t)b * Sq + q0 + m16) * Dq + h * DHq + quad * 4);

    const _Float16* kbase  = k  + ((size_t)b * Sq) * Dq + h * DHq + quad * 4;
    const _Float16* vtbase = vt + ((size_t)bh * DHq + m16) * Sq + quad * 4;

    f32x4 oacc = (f32x4)0.f;
    float lacc = 0.f;

    #pragma unroll 4
    for (int kt = 0; kt < 64; ++kt) {
        // K fragment (A-operand): K[key=m16][dh=quad*4+j]
        const f16x4 kf = *(const f16x4*)(kbase + (size_t)(kt * 16 + m16) * Dq);
        // V fragment (B-operand): V[key=kt*16+quad*4+j][dh=m16]
        const f16x4 vf = *(const f16x4*)(vtbase + kt * 16);

        f32x4 st = __builtin_amdgcn_mfma_f32_16x16x16f16(kf, qf, (f32x4)0.f, 0, 0, 0);

        float p0 = __expf(st[0] * 0.25f);
        float p1 = __expf(st[1] * 0.25f);
        float p2 = __expf(st[2] * 0.25f);
        float p3 = __expf(st[3] * 0.25f);
        lacc += (p0 + p1) + (p2 + p3);

        f16x4 pf;
        pf[0] = (_Float16)p0; pf[1] = (_Float16)p1;
        pf[2] = (_Float16)p2; pf[3] = (_Float16)p3;

        oacc = __builtin_amdgcn_mfma_f32_16x16x16f16(pf, vf, oacc, 0, 0, 0);
    }

    // full per-query softmax denominator: sum across the 4 quads
    lacc += __shfl_xor(lacc, 16, 64);
    lacc += __shfl_xor(lacc, 32, 64);   // every lane now has lsum[q = m16]

    #pragma unroll
    for (int r = 0; r < 4; ++r) {
        const float ls = __shfl(lacc, quad * 4 + r, 64);   // lsum for q=quad*4+r
        o[((size_t)b * Sq + q0 + quad * 4 + r) * Dq + h * DHq + m16] = oacc[r] / ls;
    }
}

// ---------------------------------------------------------------------------
// out = LayerNorm(a + res)*g + b; writes fp32 + bf16 copies.
// One wave per 128-dim row, 4 rows/block.
// ---------------------------------------------------------------------------
__global__ __launch_bounds__(256) void add_ln_kernel(
    const float* __restrict__ a, const float* __restrict__ res,
    const float* __restrict__ g, const float* __restrict__ bb,
    float* __restrict__ out, ushort* __restrict__ out_bf, float eps)
{
    const int wave = threadIdx.x >> 6;
    const int lane = threadIdx.x & 63;
    const int row  = blockIdx.x * 4 + wave;
    const size_t base = (size_t)row * Dq;

    float v0 = a[base + lane]      + res[base + lane];
    float v1 = a[base + 64 + lane] + res[base + 64 + lane];

    float s = v0 + v1;
    #pragma unroll
    for (int off = 32; off > 0; off >>= 1) s += __shfl_xor(s, off, 64);
    const float mu = s * (1.f / 128.f);

    const float d0 = v0 - mu, d1 = v1 - mu;
    float vs = d0 * d0 + d1 * d1;
    #pragma unroll
    for (int off = 32; off > 0; off >>= 1) vs += __shfl_xor(vs, off, 64);
    const float rstd = rsqrtf(vs * (1.f / 128.f) + eps);

    const float r0 = g[lane]      * d0 * rstd + bb[lane];
    const float r1 = g[lane + 64] * d1 * rstd + bb[lane + 64];
    out[base + lane]          = r0;
    out[base + 64 + lane]     = r1;
    out_bf[base + lane]       = f32_to_bf16(r0);
    out_bf[base + 64 + lane]  = f32_to_bf16(r1);
}

// ---------------------------------------------------------------------------
__global__ __launch_bounds__(256) void final_proj_kernel(
    const float* __restrict__ x, const float* __restrict__ Wout,
    const float* __restrict__ bout, float* __restrict__ out)
{
    const int gid = blockIdx.x * 256 + threadIdx.x;
    const int row = gid >> 3;
    const int c   = gid & 7;
    if (row >= NROWS || c >= NCLS) return;
    const float* xr = x + (size_t)row * Dq;
    float acc = bout[c];
    #pragma unroll 16
    for (int kk = 0; kk < Dq; ++kk) acc += xr[kk] * Wout[kk * NCLS + c];
    out[(size_t)row * NCLS + c] = acc;
}

// ---------------------------------------------------------------------------
extern "C" void kernel_launch(void* const* d_in, const int* in_sizes, int n_in,
                              void* d_out, int out_size, void* d_ws, size_t ws_size,
                              hipStream_t stream)
{
    const float* x_in  = (const float*)d_in[0];
    const float* Wq    = (const float*)d_in[1];
    const float* bq    = (const float*)d_in[2];
    const float* Wk    = (const float*)d_in[3];
    const float* bk    = (const float*)d_in[4];
    const float* Wv    = (const float*)d_in[5];
    const float* bv    = (const float*)d_in[6];
    const float* ln1_g = (const float*)d_in[7];
    const float* ln1_b = (const float*)d_in[8];
    const float* W1    = (const float*)d_in[9];
    const float* b1    = (const float*)d_in[10];
    const float* W2    = (const float*)d_in[11];
    const float* b2    = (const float*)d_in[12];
    const float* ln2_g = (const float*)d_in[13];
    const float* ln2_b = (const float*)d_in[14];
    const float* Wout  = (const float*)d_in[15];
    const float* bout  = (const float*)d_in[16];
    float* out = (float*)d_out;

    // Workspace layout (float units). h_bf (2NX) aliases q/k/vt/obuf-front,
    // all dead by FFN1 time. Total ~7.13NX = 59.8 MB.
    float* ws = (float*)d_ws;
    _Float16* qf16 = (_Float16*)ws;                         // NX f16 = NX/2 fl
    _Float16* kf16 = (_Float16*)(ws + NX / 2);
    _Float16* vt16 = (_Float16*)(ws + NX);                  // [b][h][dh][s]
    float*    obuf = ws + 3 * NX / 2;                       // NX f32
    ushort*   h_bf = (ushort*)ws;                           // 2NX fl worth
    float*    fbuf = ws + 5 * NX / 2;
    float*    xa   = ws + 7 * NX / 2;
    float*    xb   = ws + 9 * NX / 2;
    ushort*   xbf0 = (ushort*)(ws + 11 * NX / 2);
    ushort*   xabf = (ushort*)(ws + 6 * NX);
    ushort*   xbbf = (ushort*)(ws + 13 * NX / 2);
    ushort*   wbf  = (ushort*)(ws + 7 * NX);                // 540,672 bf16

    // prep: weight transpose+cast, x cast (same work every call)
    prep_kernel<<<dim3(10304), dim3(256), 0, stream>>>(Wq, Wk, Wv, W1, W2, x_in, wbf, xbf0);

    const dim3 blk(256);
    const float* xcur = x_in;
    const ushort* xcur_bf = xbf0;

    for (int l = 0; l < Lq; ++l) {
        const ushort* wqt = wbf + (size_t)(0 * 3 + l) * 16384;
        const ushort* wkt = wbf + (size_t)(1 * 3 + l) * 16384;
        const ushort* wvt = wbf + (size_t)(2 * 3 + l) * 16384;
        const ushort* w1t = wbf + 147456 + (size_t)l * 65536;
        const ushort* w2t = wbf + 344064 + (size_t)l * 65536;

        gemm_mfma<<<dim3(256, 1), blk, 0, stream>>>(xcur_bf, wqt, bq + l * Dq, qf16, Dq, Dq, 0);
        gemm_mfma<<<dim3(256, 1), blk, 0, stream>>>(xcur_bf, wkt, bk + l * Dq, kf16, Dq, Dq, 0);
        gemm_mfma<<<dim3(256, 1), blk, 0, stream>>>(xcur_bf, wvt, bv + l * Dq, vt16, Dq, Dq, 1);

        attn_mfma<<<dim3(Bq * Hq, 16), blk, 0, stream>>>(qf16, kf16, vt16, obuf);

        add_ln_kernel<<<dim3(NROWS / 4), blk, 0, stream>>>(
            obuf, xcur, ln1_g + l * Dq, ln1_b + l * Dq, xa, xabf, 1e-8f);

        gemm_mfma<<<dim3(256, 4), blk, 0, stream>>>(xabf, w1t, b1 + l * DFFq, h_bf, Dq, DFFq, 2);
        gemm_mfma<<<dim3(256, 1), blk, 0, stream>>>(h_bf, w2t, b2 + l * Dq, fbuf, DFFq, Dq, 3);

        add_ln_kernel<<<dim3(NROWS / 4), blk, 0, stream>>>(
            fbuf, xa, ln2_g + l * Dq, ln2_b + l * Dq, xb, xbbf, 1e-6f);

        xcur = xb;
        xcur_bf = xbbf;
    }

    final_proj_kernel<<<dim3(NROWS * 8 / 256), blk, 0, stream>>>(xcur, Wout, bout, out);
}

// Round 6
// 334.501 us; speedup vs baseline: 17.2657x; 2.1108x over previous
//
#include <hip/hip_runtime.h>
#include <math.h>

#define Bq 16
#define Sq 1024
#define Dq 128
#define Hq 8
#define DHq 16
#define DFFq 512
#define Lq 3
#define NCLS 6
#define NROWS (Bq * Sq)       // 16384
#define NX ((size_t)NROWS * Dq)   // 2,097,152 floats

typedef __attribute__((ext_vector_type(8))) short    bf16x8;
typedef __attribute__((ext_vector_type(4))) float    f32x4;
typedef __attribute__((ext_vector_type(4))) _Float16 f16x4;
typedef __attribute__((ext_vector_type(8))) _Float16 f16x8;

__device__ inline ushort f32_to_bf16(float f) {
    union { float f; unsigned u; } v; v.f = f;
    unsigned r = v.u + 0x7fffu + ((v.u >> 16) & 1u);
    return (ushort)(r >> 16);
}

// ---------------------------------------------------------------------------
// prep: cast+transpose weights to bf16 Wt[n][k]; cast x to bf16.
// ---------------------------------------------------------------------------
__global__ __launch_bounds__(256) void prep_kernel(
    const float* __restrict__ Wqp, const float* __restrict__ Wkp,
    const float* __restrict__ Wvp, const float* __restrict__ W1p,
    const float* __restrict__ W2p, const float* __restrict__ xp,
    ushort* __restrict__ wbf, ushort* __restrict__ xbf)
{
    const int gid = blockIdx.x * 256 + threadIdx.x;
    if (gid < 147456) {                       // QKV transpose
        const int w   = gid / 49152;
        const int rem = gid - w * 49152;
        const int l   = rem >> 14;
        const int idx = rem & 16383;
        const int k   = idx >> 7;
        const int n   = idx & 127;
        const float* src = (w == 0) ? Wqp : (w == 1) ? Wkp : Wvp;
        wbf[(size_t)(w * 3 + l) * 16384 + n * 128 + k] =
            f32_to_bf16(src[(size_t)l * 16384 + k * 128 + n]);
    } else if (gid < 344064) {                // W1 [128][512]->[512][128]
        const int g   = gid - 147456;
        const int l   = g >> 16;
        const int idx = g & 65535;
        const int k   = idx >> 9;
        const int n   = idx & 511;
        wbf[147456 + (size_t)l * 65536 + n * 128 + k] =
            f32_to_bf16(W1p[(size_t)l * 65536 + k * 512 + n]);
    } else if (gid < 540672) {                // W2 [512][128]->[128][512]
        const int g   = gid - 344064;
        const int l   = g >> 16;
        const int idx = g & 65535;
        const int k   = idx >> 7;
        const int n   = idx & 127;
        wbf[344064 + (size_t)l * 65536 + n * 512 + k] =
            f32_to_bf16(W2p[(size_t)l * 65536 + k * 128 + n]);
    } else {                                  // x cast
        const int g = gid - 540672;
        xbf[g] = f32_to_bf16(xp[g]);
    }
}

// ---------------------------------------------------------------------------
// Fused QKV GEMM: grid (256, 3). blockIdx.y selects weight/bias/output.
// Tile 64x128, BK=32, 4 waves, wave (wm,wn) -> 32x64 via 2x4 16x16x32 MFMAs.
// y=0: Q relu -> q16 [b,h,s,dh] f16   y=1: K relu -> k16 [b,h,s,dh] f16
// y=2: V relu -> vt16 [b,h,dh,s] f16
// ---------------------------------------------------------------------------
__global__ __launch_bounds__(256) void gemm_qkv(
    const ushort* __restrict__ A,
    const ushort* __restrict__ wq, const ushort* __restrict__ wk,
    const ushort* __restrict__ wv,
    const float* __restrict__ bqp, const float* __restrict__ bkp,
    const float* __restrict__ bvp,
    _Float16* __restrict__ qo, _Float16* __restrict__ ko,
    _Float16* __restrict__ vo)
{
    __shared__ ushort As[64 * 40];
    __shared__ ushort Bs[128 * 40];

    const int sel  = blockIdx.y;
    const ushort* Bt   = (sel == 0) ? wq : (sel == 1) ? wk : wv;
    const float*  bias = (sel == 0) ? bqp : (sel == 1) ? bkp : bvp;

    const int tid  = threadIdx.x;
    const int row0 = blockIdx.x * 64;
    const int wave = tid >> 6;
    const int lane = tid & 63;
    const int quad = lane >> 4;
    const int m16  = lane & 15;
    const int wm   = wave >> 1;
    const int wn   = wave & 1;

    const int sar = tid >> 2;
    const int sac = (tid & 3) * 8;

    f32x4 acc[2][4];
    #pragma unroll
    for (int i = 0; i < 2; ++i)
        #pragma unroll
        for (int j = 0; j < 4; ++j) acc[i][j] = (f32x4)0.f;

    for (int k0 = 0; k0 < 128; k0 += 32) {
        bf16x8 av = *(const bf16x8*)(A + (size_t)(row0 + sar) * 128 + k0 + sac);
        const int r1 = tid >> 2, r2 = r1 + 64;
        bf16x8 bv1 = *(const bf16x8*)(Bt + (size_t)r1 * 128 + k0 + sac);
        bf16x8 bv2 = *(const bf16x8*)(Bt + (size_t)r2 * 128 + k0 + sac);

        __syncthreads();
        *(bf16x8*)&As[sar * 40 + sac] = av;
        *(bf16x8*)&Bs[r1 * 40 + sac]  = bv1;
        *(bf16x8*)&Bs[r2 * 40 + sac]  = bv2;
        __syncthreads();

        bf16x8 af[2], bf[4];
        #pragma unroll
        for (int i = 0; i < 2; ++i)
            af[i] = *(const bf16x8*)&As[(32 * wm + 16 * i + m16) * 40 + quad * 8];
        #pragma unroll
        for (int j = 0; j < 4; ++j)
            bf[j] = *(const bf16x8*)&Bs[(64 * wn + 16 * j + m16) * 40 + quad * 8];
        #pragma unroll
        for (int i = 0; i < 2; ++i)
            #pragma unroll
            for (int j = 0; j < 4; ++j)
                acc[i][j] = __builtin_amdgcn_mfma_f32_16x16x32_bf16(af[i], bf[j], acc[i][j], 0, 0, 0);
    }

    _Float16* outp = (sel == 0) ? qo : (sel == 1) ? ko : vo;

    #pragma unroll
    for (int i = 0; i < 2; ++i) {
        #pragma unroll
        for (int j = 0; j < 4; ++j) {
            const int col = 64 * wn + 16 * j + m16;
            const float bb = bias[col];
            const int hh = col >> 4, dh = col & 15;
            #pragma unroll
            for (int r = 0; r < 4; ++r) {
                float val = fmaxf(acc[i][j][r] + bb, 0.f);
                const int gr = row0 + 32 * wm + 16 * i + quad * 4 + r;
                const int b = gr >> 10, s = gr & 1023;
                if (sel == 2) {
                    vo[(((size_t)b * Hq + hh) * DHq + dh) * Sq + s] = (_Float16)val;
                } else {
                    outp[(((size_t)b * Hq + hh) * Sq + s) * DHq + dh] = (_Float16)val;
                }
            }
        }
    }
}

// ---------------------------------------------------------------------------
// bf16 MFMA GEMM (FFN): C = act(A @ Bt^T + bias), tile 64x128, BK=32.
// mode: 2 relu->bf16 [M][ldo] | 3 linear->f32 [M][ldo]
// ---------------------------------------------------------------------------
__global__ __launch_bounds__(256) void gemm_mfma(
    const ushort* __restrict__ A, const ushort* __restrict__ Bt,
    const float* __restrict__ bias, void* __restrict__ out,
    int K, int ldo, int mode)
{
    __shared__ ushort As[64 * 40];
    __shared__ ushort Bs[128 * 40];

    const int tid  = threadIdx.x;
    const int row0 = blockIdx.x * 64;
    const int col0 = blockIdx.y * 128;
    const int wave = tid >> 6;
    const int lane = tid & 63;
    const int quad = lane >> 4;
    const int m16  = lane & 15;
    const int wm   = wave >> 1;
    const int wn   = wave & 1;

    const int sar = tid >> 2;
    const int sac = (tid & 3) * 8;

    f32x4 acc[2][4];
    #pragma unroll
    for (int i = 0; i < 2; ++i)
        #pragma unroll
        for (int j = 0; j < 4; ++j) acc[i][j] = (f32x4)0.f;

    for (int k0 = 0; k0 < K; k0 += 32) {
        bf16x8 av = *(const bf16x8*)(A + (size_t)(row0 + sar) * K + k0 + sac);
        const int r1 = tid >> 2, r2 = r1 + 64;
        bf16x8 bv1 = *(const bf16x8*)(Bt + (size_t)(col0 + r1) * K + k0 + sac);
        bf16x8 bv2 = *(const bf16x8*)(Bt + (size_t)(col0 + r2) * K + k0 + sac);

        __syncthreads();
        *(bf16x8*)&As[sar * 40 + sac] = av;
        *(bf16x8*)&Bs[r1 * 40 + sac]  = bv1;
        *(bf16x8*)&Bs[r2 * 40 + sac]  = bv2;
        __syncthreads();

        bf16x8 af[2], bf[4];
        #pragma unroll
        for (int i = 0; i < 2; ++i)
            af[i] = *(const bf16x8*)&As[(32 * wm + 16 * i + m16) * 40 + quad * 8];
        #pragma unroll
        for (int j = 0; j < 4; ++j)
            bf[j] = *(const bf16x8*)&Bs[(64 * wn + 16 * j + m16) * 40 + quad * 8];
        #pragma unroll
        for (int i = 0; i < 2; ++i)
            #pragma unroll
            for (int j = 0; j < 4; ++j)
                acc[i][j] = __builtin_amdgcn_mfma_f32_16x16x32_bf16(af[i], bf[j], acc[i][j], 0, 0, 0);
    }

    #pragma unroll
    for (int i = 0; i < 2; ++i) {
        #pragma unroll
        for (int j = 0; j < 4; ++j) {
            const int col = col0 + 64 * wn + 16 * j + m16;
            const float bb = bias[col];
            #pragma unroll
            for (int r = 0; r < 4; ++r) {
                float val = acc[i][j][r] + bb;
                if (mode != 3) val = fmaxf(val, 0.f);
                const int gr = row0 + 32 * wm + 16 * i + quad * 4 + r;
                if (mode == 2) {
                    ((ushort*)out)[(size_t)gr * ldo + col] = f32_to_bf16(val);
                } else {
                    ((float*)out)[(size_t)gr * ldo + col] = val;
                }
            }
        }
    }
}

// ---------------------------------------------------------------------------
// f16 MFMA flash attention, LDS-staged. grid(bh=128, qc=8), block 256.
// Q,K layout [b,h,s,dh] f16 (head-contiguous), V^T [b,h,dh,s] f16.
// Per block: 128 queries (wave: 32 = 2 frags). Outer loop stages 256-key
// K (rows padded to 20 f16) + V^T (rows padded to 264 f16) tiles in LDS;
// inner loop: 16-key subtiles, 2 QK MFMA + 2 PV MFMA sharing kf/vf.
// P^T C-layout == PV A-operand layout (verified R5: absmax passed).
// No max-subtraction (validated R2/R3/R5).
// ---------------------------------------------------------------------------
__global__ __launch_bounds__(256) void attn_mfma(
    const _Float16* __restrict__ q, const _Float16* __restrict__ k,
    const _Float16* __restrict__ vt, float* __restrict__ o)
{
    __shared__ _Float16 Ks[256 * 20];
    __shared__ _Float16 Vs[16 * 264];

    const int bh   = blockIdx.x;
    const int qc   = blockIdx.y;
    const int b    = bh >> 3;
    const int h    = bh & 7;
    const int tid  = threadIdx.x;
    const int wave = tid >> 6;
    const int lane = tid & 63;
    const int quad = lane >> 4;
    const int m16  = lane & 15;
    const int q0   = qc * 128 + wave * 32;

    // Q fragments (B-operand): Q[q][dh=quad*4+j]
    const f16x4 qf0 = *(const f16x4*)(q + (((size_t)bh * Sq) + q0 + m16) * DHq + quad * 4);
    const f16x4 qf1 = *(const f16x4*)(q + (((size_t)bh * Sq) + q0 + 16 + m16) * DHq + quad * 4);

    const _Float16* kg  = k  + (size_t)bh * Sq * DHq;       // [s][dh]
    const _Float16* vtg = vt + (size_t)bh * DHq * Sq;       // [dh][s]

    f32x4 oacc0 = (f32x4)0.f, oacc1 = (f32x4)0.f;
    float lacc0 = 0.f, lacc1 = 0.f;

    const int krow = tid;                // staging: thread t -> key row t
    const int vrow = tid >> 4;           // V row (dh)
    const int vcol = (tid & 15) * 16;    // V col block

    for (int kb = 0; kb < 4; ++kb) {
        // ---- stage 256-key tile ----
        f16x8 ka = *(const f16x8*)(kg + ((size_t)kb * 256 + krow) * DHq);
        f16x8 kb8 = *(const f16x8*)(kg + ((size_t)kb * 256 + krow) * DHq + 8);
        f16x8 va = *(const f16x8*)(vtg + (size_t)vrow * Sq + kb * 256 + vcol);
        f16x8 vb = *(const f16x8*)(vtg + (size_t)vrow * Sq + kb * 256 + vcol + 8);
        __syncthreads();
        *(f16x8*)&Ks[krow * 20 + 0] = ka;
        *(f16x8*)&Ks[krow * 20 + 8] = kb8;
        *(f16x8*)&Vs[vrow * 264 + vcol + 0] = va;
        *(f16x8*)&Vs[vrow * 264 + vcol + 8] = vb;
        __syncthreads();

        // ---- 16 subtiles of 16 keys ----
        #pragma unroll 4
        for (int kt = 0; kt < 16; ++kt) {
            const f16x4 kf = *(const f16x4*)&Ks[(kt * 16 + m16) * 20 + quad * 4];
            const f16x4 vf = *(const f16x4*)&Vs[m16 * 264 + kt * 16 + quad * 4];

            f32x4 st0 = __builtin_amdgcn_mfma_f32_16x16x16f16(kf, qf0, (f32x4)0.f, 0, 0, 0);
            f32x4 st1 = __builtin_amdgcn_mfma_f32_16x16x16f16(kf, qf1, (f32x4)0.f, 0, 0, 0);

            float p00 = __expf(st0[0] * 0.25f);
            float p01 = __expf(st0[1] * 0.25f);
            float p02 = __expf(st0[2] * 0.25f);
            float p03 = __expf(st0[3] * 0.25f);
            float p10 = __expf(st1[0] * 0.25f);
            float p11 = __expf(st1[1] * 0.25f);
            float p12 = __expf(st1[2] * 0.25f);
            float p13 = __expf(st1[3] * 0.25f);
            lacc0 += (p00 + p01) + (p02 + p03);
            lacc1 += (p10 + p11) + (p12 + p13);

            f16x4 pf0, pf1;
            pf0[0] = (_Float16)p00; pf0[1] = (_Float16)p01;
            pf0[2] = (_Float16)p02; pf0[3] = (_Float16)p03;
            pf1[0] = (_Float16)p10; pf1[1] = (_Float16)p11;
            pf1[2] = (_Float16)p12; pf1[3] = (_Float16)p13;

            oacc0 = __builtin_amdgcn_mfma_f32_16x16x16f16(pf0, vf, oacc0, 0, 0, 0);
            oacc1 = __builtin_amdgcn_mfma_f32_16x16x16f16(pf1, vf, oacc1, 0, 0, 0);
        }
    }

    // per-query softmax denominators: sum across quads
    lacc0 += __shfl_xor(lacc0, 16, 64);
    lacc0 += __shfl_xor(lacc0, 32, 64);
    lacc1 += __shfl_xor(lacc1, 16, 64);
    lacc1 += __shfl_xor(lacc1, 32, 64);

    #pragma unroll
    for (int r = 0; r < 4; ++r) {
        const float ls0 = __shfl(lacc0, quad * 4 + r, 64);
        const float ls1 = __shfl(lacc1, quad * 4 + r, 64);
        o[((size_t)b * Sq + q0 + quad * 4 + r) * Dq + h * DHq + m16]      = oacc0[r] / ls0;
        o[((size_t)b * Sq + q0 + 16 + quad * 4 + r) * Dq + h * DHq + m16] = oacc1[r] / ls1;
    }
}

// ---------------------------------------------------------------------------
// out = LayerNorm(a + res)*g + b; writes fp32 + bf16 copies.
// ---------------------------------------------------------------------------
__global__ __launch_bounds__(256) void add_ln_kernel(
    const float* __restrict__ a, const float* __restrict__ res,
    const float* __restrict__ g, const float* __restrict__ bb,
    float* __restrict__ out, ushort* __restrict__ out_bf, float eps)
{
    const int wave = threadIdx.x >> 6;
    const int lane = threadIdx.x & 63;
    const int row  = blockIdx.x * 4 + wave;
    const size_t base = (size_t)row * Dq;

    float v0 = a[base + lane]      + res[base + lane];
    float v1 = a[base + 64 + lane] + res[base + 64 + lane];

    float s = v0 + v1;
    #pragma unroll
    for (int off = 32; off > 0; off >>= 1) s += __shfl_xor(s, off, 64);
    const float mu = s * (1.f / 128.f);

    const float d0 = v0 - mu, d1 = v1 - mu;
    float vs = d0 * d0 + d1 * d1;
    #pragma unroll
    for (int off = 32; off > 0; off >>= 1) vs += __shfl_xor(vs, off, 64);
    const float rstd = rsqrtf(vs * (1.f / 128.f) + eps);

    const float r0 = g[lane]      * d0 * rstd + bb[lane];
    const float r1 = g[lane + 64] * d1 * rstd + bb[lane + 64];
    out[base + lane]          = r0;
    out[base + 64 + lane]     = r1;
    out_bf[base + lane]       = f32_to_bf16(r0);
    out_bf[base + 64 + lane]  = f32_to_bf16(r1);
}

// ---------------------------------------------------------------------------
__global__ __launch_bounds__(256) void final_proj_kernel(
    const float* __restrict__ x, const float* __restrict__ Wout,
    const float* __restrict__ bout, float* __restrict__ out)
{
    const int gid = blockIdx.x * 256 + threadIdx.x;
    const int row = gid >> 3;
    const int c   = gid & 7;
    if (row >= NROWS || c >= NCLS) return;
    const float* xr = x + (size_t)row * Dq;
    float acc = bout[c];
    #pragma unroll 16
    for (int kk = 0; kk < Dq; ++kk) acc += xr[kk] * Wout[kk * NCLS + c];
    out[(size_t)row * NCLS + c] = acc;
}

// ---------------------------------------------------------------------------
extern "C" void kernel_launch(void* const* d_in, const int* in_sizes, int n_in,
                              void* d_out, int out_size, void* d_ws, size_t ws_size,
                              hipStream_t stream)
{
    const float* x_in  = (const float*)d_in[0];
    const float* Wq    = (const float*)d_in[1];
    const float* bq    = (const float*)d_in[2];
    const float* Wk    = (const float*)d_in[3];
    const float* bk    = (const float*)d_in[4];
    const float* Wv    = (const float*)d_in[5];
    const float* bv    = (const float*)d_in[6];
    const float* ln1_g = (const float*)d_in[7];
    const float* ln1_b = (const float*)d_in[8];
    const float* W1    = (const float*)d_in[9];
    const float* b1    = (const float*)d_in[10];
    const float* W2    = (const float*)d_in[11];
    const float* b2    = (const float*)d_in[12];
    const float* ln2_g = (const float*)d_in[13];
    const float* ln2_b = (const float*)d_in[14];
    const float* Wout  = (const float*)d_in[15];
    const float* bout  = (const float*)d_in[16];
    float* out = (float*)d_out;

    // Workspace (float units). h_bf (2NX) aliases q16/k16/vt16/obuf-front.
    float* ws = (float*)d_ws;
    _Float16* qf16 = (_Float16*)ws;                         // NX f16
    _Float16* kf16 = (_Float16*)(ws + NX / 2);
    _Float16* vt16 = (_Float16*)(ws + NX);                  // [b][h][dh][s]
    float*    obuf = ws + 3 * NX / 2;                       // NX f32
    ushort*   h_bf = (ushort*)ws;                           // 2NX floats worth
    float*    fbuf = ws + 5 * NX / 2;
    float*    xa   = ws + 7 * NX / 2;
    float*    xb   = ws + 9 * NX / 2;
    ushort*   xbf0 = (ushort*)(ws + 11 * NX / 2);
    ushort*   xabf = (ushort*)(ws + 6 * NX);
    ushort*   xbbf = (ushort*)(ws + 13 * NX / 2);
    ushort*   wbf  = (ushort*)(ws + 7 * NX);                // 540,672 bf16

    prep_kernel<<<dim3(10304), dim3(256), 0, stream>>>(Wq, Wk, Wv, W1, W2, x_in, wbf, xbf0);

    const dim3 blk(256);
    const float* xcur = x_in;
    const ushort* xcur_bf = xbf0;

    for (int l = 0; l < Lq; ++l) {
        const ushort* wqt = wbf + (size_t)(0 * 3 + l) * 16384;
        const ushort* wkt = wbf + (size_t)(1 * 3 + l) * 16384;
        const ushort* wvt = wbf + (size_t)(2 * 3 + l) * 16384;
        const ushort* w1t = wbf + 147456 + (size_t)l * 65536;
        const ushort* w2t = wbf + 344064 + (size_t)l * 65536;

        gemm_qkv<<<dim3(256, 3), blk, 0, stream>>>(
            xcur_bf, wqt, wkt, wvt, bq + l * Dq, bk + l * Dq, bv + l * Dq,
            qf16, kf16, vt16);

        attn_mfma<<<dim3(Bq * Hq, 8), blk, 0, stream>>>(qf16, kf16, vt16, obuf);

        add_ln_kernel<<<dim3(NROWS / 4), blk, 0, stream>>>(
            obuf, xcur, ln1_g + l * Dq, ln1_b + l * Dq, xa, xabf, 1e-8f);

        gemm_mfma<<<dim3(256, 4), blk, 0, stream>>>(xabf, w1t, b1 + l * DFFq, h_bf, Dq, DFFq, 2);
        gemm_mfma<<<dim3(256, 1), blk, 0, stream>>>(h_bf, w2t, b2 + l * Dq, fbuf, DFFq, Dq, 3);

        add_ln_kernel<<<dim3(NROWS / 4), blk, 0, stream>>>(
            fbuf, xa, ln2_g + l * Dq, ln2_b + l * Dq, xb, xbbf, 1e-6f);

        xcur = xb;
        xcur_bf = xbbf;
    }

    final_proj_kernel<<<dim3(NROWS * 8 / 256), blk, 0, stream>>>(xcur, Wout, bout, out);
}

// Round 7
// 313.154 us; speedup vs baseline: 18.4427x; 1.0682x over previous
//
#include <hip/hip_runtime.h>
#include <math.h>

#define Bq 16
#define Sq 1024
#define Dq 128
#define Hq 8
#define DHq 16
#define DFFq 512
#define Lq 3
#define NCLS 6
#define NROWS (Bq * Sq)       // 16384
#define NX ((size_t)NROWS * Dq)   // 2,097,152 floats

typedef __attribute__((ext_vector_type(8))) short    bf16x8;
typedef __attribute__((ext_vector_type(4))) float    f32x4;
typedef __attribute__((ext_vector_type(4))) _Float16 f16x4;
typedef __attribute__((ext_vector_type(8))) _Float16 f16x8;

__device__ inline ushort f32_to_bf16(float f) {
    union { float f; unsigned u; } v; v.f = f;
    unsigned r = v.u + 0x7fffu + ((v.u >> 16) & 1u);
    return (ushort)(r >> 16);
}

// ---------------------------------------------------------------------------
// prep: cast+transpose weights to bf16 Wt[n][k]; cast x to bf16.
// Wq is PRE-SCALED by 0.25 (attention score scale; ReLU commutes with
// positive scale, bias scaled at GEMM epilogue).
// ---------------------------------------------------------------------------
__global__ __launch_bounds__(256) void prep_kernel(
    const float* __restrict__ Wqp, const float* __restrict__ Wkp,
    const float* __restrict__ Wvp, const float* __restrict__ W1p,
    const float* __restrict__ W2p, const float* __restrict__ xp,
    ushort* __restrict__ wbf, ushort* __restrict__ xbf)
{
    const int gid = blockIdx.x * 256 + threadIdx.x;
    if (gid < 147456) {                       // QKV transpose
        const int w   = gid / 49152;
        const int rem = gid - w * 49152;
        const int l   = rem >> 14;
        const int idx = rem & 16383;
        const int k   = idx >> 7;
        const int n   = idx & 127;
        const float* src = (w == 0) ? Wqp : (w == 1) ? Wkp : Wvp;
        const float scl = (w == 0) ? 0.25f : 1.0f;
        wbf[(size_t)(w * 3 + l) * 16384 + n * 128 + k] =
            f32_to_bf16(src[(size_t)l * 16384 + k * 128 + n] * scl);
    } else if (gid < 344064) {                // W1 [128][512]->[512][128]
        const int g   = gid - 147456;
        const int l   = g >> 16;
        const int idx = g & 65535;
        const int k   = idx >> 9;
        const int n   = idx & 511;
        wbf[147456 + (size_t)l * 65536 + n * 128 + k] =
            f32_to_bf16(W1p[(size_t)l * 65536 + k * 512 + n]);
    } else if (gid < 540672) {                // W2 [512][128]->[128][512]
        const int g   = gid - 344064;
        const int l   = g >> 16;
        const int idx = g & 65535;
        const int k   = idx >> 7;
        const int n   = idx & 127;
        wbf[344064 + (size_t)l * 65536 + n * 512 + k] =
            f32_to_bf16(W2p[(size_t)l * 65536 + k * 128 + n]);
    } else {                                  // x cast
        const int g = gid - 540672;
        xbf[g] = f32_to_bf16(xp[g]);
    }
}

// ---------------------------------------------------------------------------
// Fused QKV GEMM: grid (256, 3). blockIdx.y selects weight/bias/output.
// y=0: Q (pre-scaled 0.25) -> [b,h,s,dh] f16  y=1: K -> [b,h,s,dh] f16
// y=2: V -> vt [b,h,dh,s] f16
// ---------------------------------------------------------------------------
__global__ __launch_bounds__(256) void gemm_qkv(
    const ushort* __restrict__ A,
    const ushort* __restrict__ wq, const ushort* __restrict__ wk,
    const ushort* __restrict__ wv,
    const float* __restrict__ bqp, const float* __restrict__ bkp,
    const float* __restrict__ bvp,
    _Float16* __restrict__ qo, _Float16* __restrict__ ko,
    _Float16* __restrict__ vo)
{
    __shared__ ushort As[64 * 40];
    __shared__ ushort Bs[128 * 40];

    const int sel  = blockIdx.y;
    const ushort* Bt   = (sel == 0) ? wq : (sel == 1) ? wk : wv;
    const float*  bias = (sel == 0) ? bqp : (sel == 1) ? bkp : bvp;
    const float   bscl = (sel == 0) ? 0.25f : 1.0f;

    const int tid  = threadIdx.x;
    const int row0 = blockIdx.x * 64;
    const int wave = tid >> 6;
    const int lane = tid & 63;
    const int quad = lane >> 4;
    const int m16  = lane & 15;
    const int wm   = wave >> 1;
    const int wn   = wave & 1;

    const int sar = tid >> 2;
    const int sac = (tid & 3) * 8;

    f32x4 acc[2][4];
    #pragma unroll
    for (int i = 0; i < 2; ++i)
        #pragma unroll
        for (int j = 0; j < 4; ++j) acc[i][j] = (f32x4)0.f;

    for (int k0 = 0; k0 < 128; k0 += 32) {
        bf16x8 av = *(const bf16x8*)(A + (size_t)(row0 + sar) * 128 + k0 + sac);
        const int r1 = tid >> 2, r2 = r1 + 64;
        bf16x8 bv1 = *(const bf16x8*)(Bt + (size_t)r1 * 128 + k0 + sac);
        bf16x8 bv2 = *(const bf16x8*)(Bt + (size_t)r2 * 128 + k0 + sac);

        __syncthreads();
        *(bf16x8*)&As[sar * 40 + sac] = av;
        *(bf16x8*)&Bs[r1 * 40 + sac]  = bv1;
        *(bf16x8*)&Bs[r2 * 40 + sac]  = bv2;
        __syncthreads();

        bf16x8 af[2], bf[4];
        #pragma unroll
        for (int i = 0; i < 2; ++i)
            af[i] = *(const bf16x8*)&As[(32 * wm + 16 * i + m16) * 40 + quad * 8];
        #pragma unroll
        for (int j = 0; j < 4; ++j)
            bf[j] = *(const bf16x8*)&Bs[(64 * wn + 16 * j + m16) * 40 + quad * 8];
        #pragma unroll
        for (int i = 0; i < 2; ++i)
            #pragma unroll
            for (int j = 0; j < 4; ++j)
                acc[i][j] = __builtin_amdgcn_mfma_f32_16x16x32_bf16(af[i], bf[j], acc[i][j], 0, 0, 0);
    }

    #pragma unroll
    for (int i = 0; i < 2; ++i) {
        #pragma unroll
        for (int j = 0; j < 4; ++j) {
            const int col = 64 * wn + 16 * j + m16;
            const float bb = bias[col] * bscl;
            const int hh = col >> 4, dh = col & 15;
            #pragma unroll
            for (int r = 0; r < 4; ++r) {
                float val = fmaxf(acc[i][j][r] + bb, 0.f);
                const int gr = row0 + 32 * wm + 16 * i + quad * 4 + r;
                const int b = gr >> 10, s = gr & 1023;
                if (sel == 2) {
                    vo[(((size_t)b * Hq + hh) * DHq + dh) * Sq + s] = (_Float16)val;
                } else {
                    _Float16* outp = (sel == 0) ? qo : ko;
                    outp[(((size_t)b * Hq + hh) * Sq + s) * DHq + dh] = (_Float16)val;
                }
            }
        }
    }
}

// ---------------------------------------------------------------------------
// bf16 MFMA GEMM (FFN1): C = relu(A @ Bt^T + bias) -> bf16 [M][ldo]
// ---------------------------------------------------------------------------
__global__ __launch_bounds__(256) void gemm_mfma(
    const ushort* __restrict__ A, const ushort* __restrict__ Bt,
    const float* __restrict__ bias, ushort* __restrict__ out,
    int K, int ldo)
{
    __shared__ ushort As[64 * 40];
    __shared__ ushort Bs[128 * 40];

    const int tid  = threadIdx.x;
    const int row0 = blockIdx.x * 64;
    const int col0 = blockIdx.y * 128;
    const int wave = tid >> 6;
    const int lane = tid & 63;
    const int quad = lane >> 4;
    const int m16  = lane & 15;
    const int wm   = wave >> 1;
    const int wn   = wave & 1;

    const int sar = tid >> 2;
    const int sac = (tid & 3) * 8;

    f32x4 acc[2][4];
    #pragma unroll
    for (int i = 0; i < 2; ++i)
        #pragma unroll
        for (int j = 0; j < 4; ++j) acc[i][j] = (f32x4)0.f;

    for (int k0 = 0; k0 < K; k0 += 32) {
        bf16x8 av = *(const bf16x8*)(A + (size_t)(row0 + sar) * K + k0 + sac);
        const int r1 = tid >> 2, r2 = r1 + 64;
        bf16x8 bv1 = *(const bf16x8*)(Bt + (size_t)(col0 + r1) * K + k0 + sac);
        bf16x8 bv2 = *(const bf16x8*)(Bt + (size_t)(col0 + r2) * K + k0 + sac);

        __syncthreads();
        *(bf16x8*)&As[sar * 40 + sac] = av;
        *(bf16x8*)&Bs[r1 * 40 + sac]  = bv1;
        *(bf16x8*)&Bs[r2 * 40 + sac]  = bv2;
        __syncthreads();

        bf16x8 af[2], bf[4];
        #pragma unroll
        for (int i = 0; i < 2; ++i)
            af[i] = *(const bf16x8*)&As[(32 * wm + 16 * i + m16) * 40 + quad * 8];
        #pragma unroll
        for (int j = 0; j < 4; ++j)
            bf[j] = *(const bf16x8*)&Bs[(64 * wn + 16 * j + m16) * 40 + quad * 8];
        #pragma unroll
        for (int i = 0; i < 2; ++i)
            #pragma unroll
            for (int j = 0; j < 4; ++j)
                acc[i][j] = __builtin_amdgcn_mfma_f32_16x16x32_bf16(af[i], bf[j], acc[i][j], 0, 0, 0);
    }

    #pragma unroll
    for (int i = 0; i < 2; ++i) {
        #pragma unroll
        for (int j = 0; j < 4; ++j) {
            const int col = col0 + 64 * wn + 16 * j + m16;
            const float bb = bias[col];
            #pragma unroll
            for (int r = 0; r < 4; ++r) {
                float val = fmaxf(acc[i][j][r] + bb, 0.f);
                const int gr = row0 + 32 * wm + 16 * i + quad * 4 + r;
                out[(size_t)gr * ldo + col] = f32_to_bf16(val);
            }
        }
    }
}

// ---------------------------------------------------------------------------
// Fused FFN2 + residual + LayerNorm2: block tile 64 rows x 128 cols = FULL
// rows, so LN completes in-block. Phases: (1) MFMA K-loop (K=512),
// (2) vals = acc+bias+resid -> LDS f32 [64][129], (3) threads 0..63 reduce
// mu/rstd per row, (4) apply gamma/beta, write xb fp32 + xbbf bf16.
// LDS: staging (15360 B) aliased under the vals buffer (33536 B).
// ---------------------------------------------------------------------------
__global__ __launch_bounds__(256) void gemm_ffn2_ln(
    const ushort* __restrict__ A, const ushort* __restrict__ Bt,
    const float* __restrict__ bias, const float* __restrict__ resid,
    const float* __restrict__ g, const float* __restrict__ beta,
    float* __restrict__ xb, ushort* __restrict__ xbbf)
{
    __shared__ __align__(16) char smem_raw[33536];
    ushort* As   = (ushort*)smem_raw;            // 64*40  = 2560 ushorts
    ushort* Bs   = (ushort*)smem_raw + 2560;     // 128*40 = 5120 ushorts
    float*  vals = (float*)smem_raw;             // [64][129]
    float*  mus  = (float*)smem_raw + 8256;      // [64]
    float*  rsds = (float*)smem_raw + 8320;      // [64]

    const int tid  = threadIdx.x;
    const int row0 = blockIdx.x * 64;
    const int wave = tid >> 6;
    const int lane = tid & 63;
    const int quad = lane >> 4;
    const int m16  = lane & 15;
    const int wm   = wave >> 1;
    const int wn   = wave & 1;

    const int sar = tid >> 2;
    const int sac = (tid & 3) * 8;

    f32x4 acc[2][4];
    #pragma unroll
    for (int i = 0; i < 2; ++i)
        #pragma unroll
        for (int j = 0; j < 4; ++j) acc[i][j] = (f32x4)0.f;

    for (int k0 = 0; k0 < DFFq; k0 += 32) {
        bf16x8 av = *(const bf16x8*)(A + (size_t)(row0 + sar) * DFFq + k0 + sac);
        const int r1 = tid >> 2, r2 = r1 + 64;
        bf16x8 bv1 = *(const bf16x8*)(Bt + (size_t)r1 * DFFq + k0 + sac);
        bf16x8 bv2 = *(const bf16x8*)(Bt + (size_t)r2 * DFFq + k0 + sac);

        __syncthreads();
        *(bf16x8*)&As[sar * 40 + sac] = av;
        *(bf16x8*)&Bs[r1 * 40 + sac]  = bv1;
        *(bf16x8*)&Bs[r2 * 40 + sac]  = bv2;
        __syncthreads();

        bf16x8 af[2], bf[4];
        #pragma unroll
        for (int i = 0; i < 2; ++i)
            af[i] = *(const bf16x8*)&As[(32 * wm + 16 * i + m16) * 40 + quad * 8];
        #pragma unroll
        for (int j = 0; j < 4; ++j)
            bf[j] = *(const bf16x8*)&Bs[(64 * wn + 16 * j + m16) * 40 + quad * 8];
        #pragma unroll
        for (int i = 0; i < 2; ++i)
            #pragma unroll
            for (int j = 0; j < 4; ++j)
                acc[i][j] = __builtin_amdgcn_mfma_f32_16x16x32_bf16(af[i], bf[j], acc[i][j], 0, 0, 0);
    }

    __syncthreads();   // staging dead; vals buffer takes over LDS

    // phase 2: vals = acc + bias + residual -> LDS (and keep in registers)
    float vreg[2][4][4];
    #pragma unroll
    for (int i = 0; i < 2; ++i) {
        #pragma unroll
        for (int j = 0; j < 4; ++j) {
            const int col = 64 * wn + 16 * j + m16;
            const float bb = bias[col];
            #pragma unroll
            for (int r = 0; r < 4; ++r) {
                const int grow = 32 * wm + 16 * i + quad * 4 + r;
                float v = acc[i][j][r] + bb + resid[(size_t)(row0 + grow) * Dq + col];
                vreg[i][j][r] = v;
                vals[grow * 129 + col] = v;
            }
        }
    }
    __syncthreads();

    // phase 3: per-row mean/rstd (threads 0..63, one row each; stride 129
    // => 2-way max bank aliasing, free)
    if (tid < 64) {
        float s = 0.f, s2 = 0.f;
        #pragma unroll 8
        for (int c = 0; c < Dq; ++c) {
            float x = vals[tid * 129 + c];
            s += x; s2 = fmaf(x, x, s2);
        }
        const float mu  = s * (1.f / 128.f);
        const float var = s2 * (1.f / 128.f) - mu * mu;
        mus[tid]  = mu;
        rsds[tid] = rsqrtf(var + 1e-6f);
    }
    __syncthreads();

    // phase 4: apply gamma/beta, dual write
    #pragma unroll
    for (int i = 0; i < 2; ++i) {
        #pragma unroll
        for (int r = 0; r < 4; ++r) {
            const int grow = 32 * wm + 16 * i + quad * 4 + r;
            const float mu = mus[grow];
            const float rs = rsds[grow];
            #pragma unroll
            for (int j = 0; j < 4; ++j) {
                const int col = 64 * wn + 16 * j + m16;
                const float rn = g[col] * (vreg[i][j][r] - mu) * rs + beta[col];
                const size_t idx = (size_t)(row0 + grow) * Dq + col;
                xb[idx]   = rn;
                xbbf[idx] = f32_to_bf16(rn);
            }
        }
    }
}

// ---------------------------------------------------------------------------
// f16 MFMA flash attention, LDS-staged (R6 structure). Q arrives pre-scaled
// by 0.25, so p = expf(st) directly. No max-subtraction (validated R2..R6).
// ---------------------------------------------------------------------------
__global__ __launch_bounds__(256) void attn_mfma(
    const _Float16* __restrict__ q, const _Float16* __restrict__ k,
    const _Float16* __restrict__ vt, float* __restrict__ o)
{
    __shared__ _Float16 Ks[256 * 20];
    __shared__ _Float16 Vs[16 * 264];

    const int bh   = blockIdx.x;
    const int qc   = blockIdx.y;
    const int b    = bh >> 3;
    const int h    = bh & 7;
    const int tid  = threadIdx.x;
    const int wave = tid >> 6;
    const int lane = tid & 63;
    const int quad = lane >> 4;
    const int m16  = lane & 15;
    const int q0   = qc * 128 + wave * 32;

    const f16x4 qf0 = *(const f16x4*)(q + (((size_t)bh * Sq) + q0 + m16) * DHq + quad * 4);
    const f16x4 qf1 = *(const f16x4*)(q + (((size_t)bh * Sq) + q0 + 16 + m16) * DHq + quad * 4);

    const _Float16* kg  = k  + (size_t)bh * Sq * DHq;
    const _Float16* vtg = vt + (size_t)bh * DHq * Sq;

    f32x4 oacc0 = (f32x4)0.f, oacc1 = (f32x4)0.f;
    float lacc0 = 0.f, lacc1 = 0.f;

    const int krow = tid;
    const int vrow = tid >> 4;
    const int vcol = (tid & 15) * 16;

    for (int kb = 0; kb < 4; ++kb) {
        f16x8 ka  = *(const f16x8*)(kg + ((size_t)kb * 256 + krow) * DHq);
        f16x8 kb8 = *(const f16x8*)(kg + ((size_t)kb * 256 + krow) * DHq + 8);
        f16x8 va  = *(const f16x8*)(vtg + (size_t)vrow * Sq + kb * 256 + vcol);
        f16x8 vb  = *(const f16x8*)(vtg + (size_t)vrow * Sq + kb * 256 + vcol + 8);
        __syncthreads();
        *(f16x8*)&Ks[krow * 20 + 0] = ka;
        *(f16x8*)&Ks[krow * 20 + 8] = kb8;
        *(f16x8*)&Vs[vrow * 264 + vcol + 0] = va;
        *(f16x8*)&Vs[vrow * 264 + vcol + 8] = vb;
        __syncthreads();

        #pragma unroll 4
        for (int kt = 0; kt < 16; ++kt) {
            const f16x4 kf = *(const f16x4*)&Ks[(kt * 16 + m16) * 20 + quad * 4];
            const f16x4 vf = *(const f16x4*)&Vs[m16 * 264 + kt * 16 + quad * 4];

            f32x4 st0 = __builtin_amdgcn_mfma_f32_16x16x16f16(kf, qf0, (f32x4)0.f, 0, 0, 0);
            f32x4 st1 = __builtin_amdgcn_mfma_f32_16x16x16f16(kf, qf1, (f32x4)0.f, 0, 0, 0);

            float p00 = __expf(st0[0]);
            float p01 = __expf(st0[1]);
            float p02 = __expf(st0[2]);
            float p03 = __expf(st0[3]);
            float p10 = __expf(st1[0]);
            float p11 = __expf(st1[1]);
            float p12 = __expf(st1[2]);
            float p13 = __expf(st1[3]);
            lacc0 += (p00 + p01) + (p02 + p03);
            lacc1 += (p10 + p11) + (p12 + p13);

            f16x4 pf0, pf1;
            pf0[0] = (_Float16)p00; pf0[1] = (_Float16)p01;
            pf0[2] = (_Float16)p02; pf0[3] = (_Float16)p03;
            pf1[0] = (_Float16)p10; pf1[1] = (_Float16)p11;
            pf1[2] = (_Float16)p12; pf1[3] = (_Float16)p13;

            oacc0 = __builtin_amdgcn_mfma_f32_16x16x16f16(pf0, vf, oacc0, 0, 0, 0);
            oacc1 = __builtin_amdgcn_mfma_f32_16x16x16f16(pf1, vf, oacc1, 0, 0, 0);
        }
    }

    lacc0 += __shfl_xor(lacc0, 16, 64);
    lacc0 += __shfl_xor(lacc0, 32, 64);
    lacc1 += __shfl_xor(lacc1, 16, 64);
    lacc1 += __shfl_xor(lacc1, 32, 64);

    #pragma unroll
    for (int r = 0; r < 4; ++r) {
        const float ls0 = __shfl(lacc0, quad * 4 + r, 64);
        const float ls1 = __shfl(lacc1, quad * 4 + r, 64);
        o[((size_t)b * Sq + q0 + quad * 4 + r) * Dq + h * DHq + m16]      = oacc0[r] / ls0;
        o[((size_t)b * Sq + q0 + 16 + quad * 4 + r) * Dq + h * DHq + m16] = oacc1[r] / ls1;
    }
}

// ---------------------------------------------------------------------------
// out = LayerNorm(a + res)*g + b; writes fp32 + bf16 copies (used for LN1).
// ---------------------------------------------------------------------------
__global__ __launch_bounds__(256) void add_ln_kernel(
    const float* __restrict__ a, const float* __restrict__ res,
    const float* __restrict__ g, const float* __restrict__ bb,
    float* __restrict__ out, ushort* __restrict__ out_bf, float eps)
{
    const int wave = threadIdx.x >> 6;
    const int lane = threadIdx.x & 63;
    const int row  = blockIdx.x * 4 + wave;
    const size_t base = (size_t)row * Dq;

    float v0 = a[base + lane]      + res[base + lane];
    float v1 = a[base + 64 + lane] + res[base + 64 + lane];

    float s = v0 + v1;
    #pragma unroll
    for (int off = 32; off > 0; off >>= 1) s += __shfl_xor(s, off, 64);
    const float mu = s * (1.f / 128.f);

    const float d0 = v0 - mu, d1 = v1 - mu;
    float vs = d0 * d0 + d1 * d1;
    #pragma unroll
    for (int off = 32; off > 0; off >>= 1) vs += __shfl_xor(vs, off, 64);
    const float rstd = rsqrtf(vs * (1.f / 128.f) + eps);

    const float r0 = g[lane]      * d0 * rstd + bb[lane];
    const float r1 = g[lane + 64] * d1 * rstd + bb[lane + 64];
    out[base + lane]          = r0;
    out[base + 64 + lane]     = r1;
    out_bf[base + lane]       = f32_to_bf16(r0);
    out_bf[base + 64 + lane]  = f32_to_bf16(r1);
}

// ---------------------------------------------------------------------------
__global__ __launch_bounds__(256) void final_proj_kernel(
    const float* __restrict__ x, const float* __restrict__ Wout,
    const float* __restrict__ bout, float* __restrict__ out)
{
    const int gid = blockIdx.x * 256 + threadIdx.x;
    const int row = gid >> 3;
    const int c   = gid & 7;
    if (row >= NROWS || c >= NCLS) return;
    const float* xr = x + (size_t)row * Dq;
    float acc = bout[c];
    #pragma unroll 16
    for (int kk = 0; kk < Dq; ++kk) acc += xr[kk] * Wout[kk * NCLS + c];
    out[(size_t)row * NCLS + c] = acc;
}

// ---------------------------------------------------------------------------
extern "C" void kernel_launch(void* const* d_in, const int* in_sizes, int n_in,
                              void* d_out, int out_size, void* d_ws, size_t ws_size,
                              hipStream_t stream)
{
    const float* x_in  = (const float*)d_in[0];
    const float* Wq    = (const float*)d_in[1];
    const float* bq    = (const float*)d_in[2];
    const float* Wk    = (const float*)d_in[3];
    const float* bk    = (const float*)d_in[4];
    const float* Wv    = (const float*)d_in[5];
    const float* bv    = (const float*)d_in[6];
    const float* ln1_g = (const float*)d_in[7];
    const float* ln1_b = (const float*)d_in[8];
    const float* W1    = (const float*)d_in[9];
    const float* b1    = (const float*)d_in[10];
    const float* W2    = (const float*)d_in[11];
    const float* b2    = (const float*)d_in[12];
    const float* ln2_g = (const float*)d_in[13];
    const float* ln2_b = (const float*)d_in[14];
    const float* Wout  = (const float*)d_in[15];
    const float* bout  = (const float*)d_in[16];
    float* out = (float*)d_out;

    // Workspace (float units). h_bf (2NX) aliases q16/k16/vt16/obuf-front.
    float* ws = (float*)d_ws;
    _Float16* qf16 = (_Float16*)ws;                         // NX f16
    _Float16* kf16 = (_Float16*)(ws + NX / 2);
    _Float16* vt16 = (_Float16*)(ws + NX);                  // [b][h][dh][s]
    float*    obuf = ws + 3 * NX / 2;                       // NX f32
    ushort*   h_bf = (ushort*)ws;                           // 2NX floats worth
    float*    xa   = ws + 7 * NX / 2;
    float*    xb   = ws + 9 * NX / 2;
    ushort*   xbf0 = (ushort*)(ws + 11 * NX / 2);
    ushort*   xabf = (ushort*)(ws + 6 * NX);
    ushort*   xbbf = (ushort*)(ws + 13 * NX / 2);
    ushort*   wbf  = (ushort*)(ws + 7 * NX);                // 540,672 bf16

    prep_kernel<<<dim3(10304), dim3(256), 0, stream>>>(Wq, Wk, Wv, W1, W2, x_in, wbf, xbf0);

    const dim3 blk(256);
    const float* xcur = x_in;
    const ushort* xcur_bf = xbf0;

    for (int l = 0; l < Lq; ++l) {
        const ushort* wqt = wbf + (size_t)(0 * 3 + l) * 16384;
        const ushort* wkt = wbf + (size_t)(1 * 3 + l) * 16384;
        const ushort* wvt = wbf + (size_t)(2 * 3 + l) * 16384;
        const ushort* w1t = wbf + 147456 + (size_t)l * 65536;
        const ushort* w2t = wbf + 344064 + (size_t)l * 65536;

        gemm_qkv<<<dim3(256, 3), blk, 0, stream>>>(
            xcur_bf, wqt, wkt, wvt, bq + l * Dq, bk + l * Dq, bv + l * Dq,
            qf16, kf16, vt16);

        attn_mfma<<<dim3(Bq * Hq, 8), blk, 0, stream>>>(qf16, kf16, vt16, obuf);

        add_ln_kernel<<<dim3(NROWS / 4), blk, 0, stream>>>(
            obuf, xcur, ln1_g + l * Dq, ln1_b + l * Dq, xa, xabf, 1e-8f);

        gemm_mfma<<<dim3(256, 4), blk, 0, stream>>>(xabf, w1t, b1 + l * DFFq, h_bf, Dq, DFFq);

        gemm_ffn2_ln<<<dim3(256), blk, 0, stream>>>(
            h_bf, w2t, b2 + l * Dq, xa, ln2_g + l * Dq, ln2_b + l * Dq, xb, xbbf);

        xcur = xb;
        xcur_bf = xbbf;
    }

    final_proj_kernel<<<dim3(NROWS * 8 / 256), blk, 0, stream>>>(xcur, Wout, bout, out);
}